// Round 1
// baseline (2073.974 us; speedup 1.0000x reference)
//
#include <hip/hip_runtime.h>
#include <math.h>

// DeltaLM: B=4 T=2048 D=512 H=4D=2048 L=3 V=256
// Key insight: decay einsum == geometric scan S[i] = h[i] + w*S[i-1],
// w = exp(-softplus(k)). w^32 ~ 6e-19 -> chunked scan with 32-step warmup.
// Heavy compute: MLP GEMMs (103 GF fp32). Round 1 = correct fp32 baseline.

constexpr int Bc = 4, Tc = 2048, Dc = 512, Hc = 2048, Vc = 256;
constexpr int TS = 128, NC = 16, WARM = 32;  // time chunking (T = TS*NC)

// ---------- kernel 1: embed gather + cumprod(feature) + tanh ----------
// one wave per token; lane owns 8 contiguous d's; multiplicative wave scan
__global__ __launch_bounds__(256) void embed_boundary(
    const int* __restrict__ x, const float* __restrict__ embed,
    float* __restrict__ th)
{
  int token = blockIdx.x * 4 + (threadIdx.x >> 6);
  int lane  = threadIdx.x & 63;
  int row = x[token];
  const float* e = embed + (size_t)row * Dc + lane * 8;
  float v[8];
  {
    float4 a = *(const float4*)e;
    float4 b = *(const float4*)(e + 4);
    v[0]=a.x; v[1]=a.y; v[2]=a.z; v[3]=a.w;
    v[4]=b.x; v[5]=b.y; v[6]=b.z; v[7]=b.w;
  }
  float p = v[0];
  #pragma unroll
  for (int j=1;j<8;++j) p *= v[j];
  float incl = p;                       // inclusive product scan across lanes
  #pragma unroll
  for (int off=1; off<64; off<<=1) {
    float t = __shfl_up(incl, off);
    if (lane >= off) incl *= t;
  }
  float excl = __shfl_up(incl, 1);
  if (lane == 0) excl = 1.0f;
  float c = excl;
  float o[8];
  #pragma unroll
  for (int j=0;j<8;++j) { c *= v[j]; o[j] = tanhf(c); }
  float* dst = th + (size_t)token * Dc + lane * 8;
  *(float4*)dst     = make_float4(o[0],o[1],o[2],o[3]);
  *(float4*)(dst+4) = make_float4(o[4],o[5],o[6],o[7]);
}

// ---------- chunk partial sums over time (for exact cumsum) ----------
__global__ __launch_bounds__(512) void part_sums(
    const float* __restrict__ src, float* __restrict__ part)
{
  int c = blockIdx.x, b = blockIdx.y, d = threadIdx.x;
  const float* p = src + ((size_t)b * Tc + c * TS) * Dc + d;
  float s = 0.f;
  for (int t=0;t<TS;++t) s += p[(size_t)t*Dc];
  part[((size_t)b*NC + c)*Dc + d] = s;
}

// ---------- bd = cumsum_t(th); h = embed[x]*(1+bd) ----------
__global__ __launch_bounds__(512) void bd_apply(
    const float* __restrict__ th, const float* __restrict__ part,
    const int* __restrict__ x, const float* __restrict__ embed,
    float* __restrict__ h)
{
  int c = blockIdx.x, b = blockIdx.y, d = threadIdx.x;
  float acc = 0.f;
  for (int cc=0; cc<c; ++cc) acc += part[((size_t)b*NC+cc)*Dc + d];
  for (int t=0;t<TS;++t) {
    int tt = c*TS + t;
    size_t idx = ((size_t)b*Tc + tt)*Dc + d;
    acc += th[idx];
    int row = x[b*Tc + tt];
    float e = embed[(size_t)row*Dc + d];
    h[idx] = e * (1.0f + acc);
  }
}

// ---------- hcum = cumsum_t(h); magsq[b,t] = ||hcum - hprev||^2 ----------
__global__ __launch_bounds__(512) void hcum_mag(
    const float* __restrict__ h, const float* __restrict__ part,
    float* __restrict__ magsq)
{
  __shared__ float red[8];
  int c = blockIdx.x, b = blockIdx.y, d = threadIdx.x;
  int lane = d & 63, wv = d >> 6;
  float acc = 0.f;
  for (int cc=0; cc<c; ++cc) acc += part[((size_t)b*NC+cc)*Dc + d];
  for (int t=0;t<TS;++t) {
    int tt = c*TS + t;
    size_t idx = ((size_t)b*Tc + tt)*Dc + d;
    acc += h[idx];
    float hp = (tt > 0) ? h[idx - Dc] : 0.f;
    float diff = acc - hp;
    float sq = diff * diff;
    #pragma unroll
    for (int off=32; off; off>>=1) sq += __shfl_down(sq, off);
    if (lane == 0) red[wv] = sq;
    __syncthreads();
    if (d == 0) {
      float s = red[0];
      #pragma unroll
      for (int i=1;i<8;++i) s += red[i];
      magsq[b*Tc + tt] = s;
    }
    __syncthreads();
  }
}

// ---------- geometric scan: ctx = mag * |S|, S = h + w*S_prev ----------
// chunked with WARM-step warmup (w^32 ~ 6e-19 relative -> exact in fp32)
__global__ __launch_bounds__(512) void scan_ctx(
    const float* __restrict__ h, const float* __restrict__ magsq,
    const float* __restrict__ kvec, int l, float* __restrict__ ctx)
{
  int c = blockIdx.x, b = blockIdx.y, d = threadIdx.x;
  float kk = kvec[l];
  float sp = kk > 0.f ? kk + log1pf(expf(-kk)) : log1pf(expf(kk));
  float w = expf(-sp);
  int t0 = c * TS;
  int ts = t0 - WARM; if (ts < 0) ts = 0;
  float s = 0.f;
  for (int t=ts; t<t0; ++t) s = h[((size_t)b*Tc + t)*Dc + d] + w*s;
  for (int t=t0; t<t0+TS; ++t) {
    size_t idx = ((size_t)b*Tc + t)*Dc + d;
    s = h[idx] + w * s;
    ctx[idx] = sqrtf(magsq[b*Tc + t]) * fabsf(s);
  }
}

// ---------- layernorm in place (eps=1e-3, two-pass) ----------
__global__ __launch_bounds__(256) void ln_inplace(
    float* __restrict__ y, const float* __restrict__ g,
    const float* __restrict__ bt, int l)
{
  __shared__ float red[4];
  int token = blockIdx.x, tid = threadIdx.x;
  int lane = tid & 63, wv = tid >> 6;
  float* p = y + (size_t)token * Dc;
  float x0 = p[tid], x1 = p[tid + 256];
  float s = x0 + x1;
  #pragma unroll
  for (int off=32; off; off>>=1) s += __shfl_down(s, off);
  if (!lane) red[wv] = s;
  __syncthreads();
  float mu = (red[0]+red[1]+red[2]+red[3]) * (1.f/Dc);
  float d0 = x0 - mu, d1 = x1 - mu;
  float s2 = d0*d0 + d1*d1;
  __syncthreads();
  #pragma unroll
  for (int off=32; off; off>>=1) s2 += __shfl_down(s2, off);
  if (!lane) red[wv] = s2;
  __syncthreads();
  float var = (red[0]+red[1]+red[2]+red[3]) * (1.f/Dc);
  float rs = rsqrtf(var + 1e-3f);
  p[tid]       = d0 * rs * g[l*Dc + tid]       + bt[l*Dc + tid];
  p[tid + 256] = d1 * rs * g[l*Dc + tid + 256] + bt[l*Dc + tid + 256];
}

// ---------- fp32 GEMM: 128x128 block tile, 8x8/thread, BK=8 ----------
// EPI: 0 = store gelu(z+bias); 1 = C += z+bias (residual into h); 2 = store z
// BT: false -> Bm is KxN row-major; true -> Bm is NxK row-major (embed^T)
constexpr int BMt = 128, BNt = 128, BKt = 8;

__device__ inline float gelu_f(float z) {
  return 0.5f * z * (1.0f + erff(z * 0.707106781186547524f));
}

template<int EPI, bool BT>
__global__ __launch_bounds__(256) void gemm(
    const float* __restrict__ A, const float* __restrict__ Bm,
    const float* __restrict__ bias, float* __restrict__ C,
    int M, int N, int K)
{
  __shared__ float As[BKt][BMt];
  __shared__ float Bs[BKt][BNt];
  int tid = threadIdx.x;
  int tx = tid & 15, ty = tid >> 4;
  int m0 = blockIdx.y * BMt, n0 = blockIdx.x * BNt;
  float acc[8][8] = {};
  int am = tid >> 1, ak = (tid & 1) << 2;     // A/BT staging map
  int kb = tid >> 5, nb = (tid & 31) << 2;    // B (KxN) staging map
  const float* Aptr = A + (size_t)(m0 + am) * K + ak;
  const float* Bptr = BT ? (Bm + (size_t)(n0 + am) * K + ak)
                         : (Bm + (size_t)kb * N + n0 + nb);

  for (int k0 = 0; k0 < K; k0 += BKt) {
    float4 a4 = *(const float4*)(Aptr + k0);
    float4 b4;
    if constexpr (BT) b4 = *(const float4*)(Bptr + k0);
    else              b4 = *(const float4*)(Bptr + (size_t)k0 * N);
    __syncthreads();
    As[ak+0][am] = a4.x; As[ak+1][am] = a4.y; As[ak+2][am] = a4.z; As[ak+3][am] = a4.w;
    if constexpr (BT) {
      Bs[ak+0][am] = b4.x; Bs[ak+1][am] = b4.y; Bs[ak+2][am] = b4.z; Bs[ak+3][am] = b4.w;
    } else {
      *(float4*)&Bs[kb][nb] = b4;
    }
    __syncthreads();
    #pragma unroll
    for (int kkk = 0; kkk < BKt; ++kkk) {
      float a[8], b[8];
      *(float4*)&a[0] = *(const float4*)&As[kkk][ty*8];
      *(float4*)&a[4] = *(const float4*)&As[kkk][ty*8+4];
      *(float4*)&b[0] = *(const float4*)&Bs[kkk][tx*8];
      *(float4*)&b[4] = *(const float4*)&Bs[kkk][tx*8+4];
      #pragma unroll
      for (int i=0;i<8;++i)
        #pragma unroll
        for (int j=0;j<8;++j)
          acc[i][j] = fmaf(a[i], b[j], acc[i][j]);
    }
  }
  int nbase = n0 + tx*8;
  #pragma unroll
  for (int i=0;i<8;++i) {
    int m = m0 + ty*8 + i;
    float* crow = C + (size_t)m * N + nbase;
    #pragma unroll
    for (int jj=0; jj<8; jj+=4) {
      float z0 = acc[i][jj], z1 = acc[i][jj+1], z2 = acc[i][jj+2], z3 = acc[i][jj+3];
      if constexpr (EPI != 2) {
        const float* bp = bias + nbase + jj;
        z0 += bp[0]; z1 += bp[1]; z2 += bp[2]; z3 += bp[3];
      }
      if constexpr (EPI == 0) { z0 = gelu_f(z0); z1 = gelu_f(z1); z2 = gelu_f(z2); z3 = gelu_f(z3); }
      if constexpr (EPI == 1) {
        z0 += crow[jj]; z1 += crow[jj+1]; z2 += crow[jj+2]; z3 += crow[jj+3];
      }
      *(float4*)&crow[jj] = make_float4(z0,z1,z2,z3);
    }
  }
}

extern "C" void kernel_launch(void* const* d_in, const int* in_sizes, int n_in,
                              void* d_out, int out_size, void* d_ws, size_t ws_size,
                              hipStream_t stream) {
  const int*   x     = (const int*)  d_in[0];
  const float* embed = (const float*)d_in[1];
  const float* kvec  = (const float*)d_in[2];
  const float* g     = (const float*)d_in[3];
  const float* bt    = (const float*)d_in[4];
  const float* W1    = (const float*)d_in[5];
  const float* b1    = (const float*)d_in[6];
  const float* W2    = (const float*)d_in[7];
  const float* b2    = (const float*)d_in[8];
  float* out = (float*)d_out;
  float* ws  = (float*)d_ws;

  const size_t NTD = (size_t)Bc * Tc * Dc;       // 4,194,304
  float* h     = ws;
  float* tmpA  = ws + NTD;                        // th -> ctx -> y0 (reused)
  float* a1    = tmpA + NTD;                      // N x H (64 MB)
  float* part  = a1 + (size_t)Bc * Tc * Hc;       // B*NC*D chunk partials
  float* magsq = part + (size_t)Bc * NC * Dc;     // B*T

  // prologue: th = tanh(cumprod(embed[x])); bd = cumsum_t(th); h = e*(1+bd)
  embed_boundary<<<dim3(Bc*Tc/4), 256, 0, stream>>>(x, embed, tmpA);
  part_sums<<<dim3(NC, Bc), 512, 0, stream>>>(tmpA, part);
  bd_apply<<<dim3(NC, Bc), 512, 0, stream>>>(tmpA, part, x, embed, h);

  for (int l = 0; l < 3; ++l) {
    part_sums<<<dim3(NC, Bc), 512, 0, stream>>>(h, part);
    hcum_mag<<<dim3(NC, Bc), 512, 0, stream>>>(h, part, magsq);
    scan_ctx<<<dim3(NC, Bc), 512, 0, stream>>>(h, magsq, kvec, l, tmpA);
    ln_inplace<<<dim3(Bc*Tc), 256, 0, stream>>>(tmpA, g, bt, l);
    // z = gelu(y0 @ W1 + b1): M=8192 N=2048 K=512
    gemm<0,false><<<dim3(Hc/BNt, Bc*Tc/BMt), 256, 0, stream>>>(
        tmpA, W1 + (size_t)l*Dc*Hc, b1 + (size_t)l*Hc, a1, Bc*Tc, Hc, Dc);
    // h += z @ W2 + b2: M=8192 N=512 K=2048
    gemm<1,false><<<dim3(Dc/BNt, Bc*Tc/BMt), 256, 0, stream>>>(
        a1, W2 + (size_t)l*Hc*Dc, b2 + (size_t)l*Dc, h, Bc*Tc, Dc, Hc);
  }
  // out = h @ embed^T: M=8192 N=256 K=512
  gemm<2,true><<<dim3(Vc/BNt, Bc*Tc/BMt), 256, 0, stream>>>(
      h, embed, nullptr, out, Bc*Tc, Vc, Dc);
}

// Round 2
// 676.780 us; speedup vs baseline: 3.0645x; 3.0645x over previous
//
#include <hip/hip_runtime.h>
#include <math.h>

// DeltaLM: B=4 T=2048 D=512 H=2048 L=3 V=256
// decay einsum == geometric scan S[i]=h[i]+w*S[i-1], w=exp(-softplus(k)),
// w^32~6e-19 -> 32-step warmup chunked scan is exact in fp32.
// Round 2: MLP GEMMs -> bf16 MFMA 16x16x32 (m97 structure) with XOR-swizzled
// LDS (2-way = free bank aliasing) + global_load_lds width=16 staging.

constexpr int Bc = 4, Tc = 2048, Dc = 512, Hc = 2048, Vc = 256;
constexpr int TS = 128, NC = 16, WARM = 32;

typedef __attribute__((ext_vector_type(8))) short short8;
typedef __attribute__((ext_vector_type(4))) float f32x4;

__device__ inline unsigned short f2bf(float f) {  // RNE fp32->bf16
  unsigned int u = __float_as_uint(f);
  u += 0x7fffu + ((u >> 16) & 1u);
  return (unsigned short)(u >> 16);
}

__device__ inline void gload_lds16(const void* g, void* l) {
  __builtin_amdgcn_global_load_lds(
      (const __attribute__((address_space(1))) void*)g,
      (__attribute__((address_space(3))) void*)l, 16, 0, 0);
}

// ---------- embed gather + cumprod(feature) + tanh ----------
__global__ __launch_bounds__(256) void embed_boundary(
    const int* __restrict__ x, const float* __restrict__ embed,
    float* __restrict__ th)
{
  int token = blockIdx.x * 4 + (threadIdx.x >> 6);
  int lane  = threadIdx.x & 63;
  int row = x[token];
  const float* e = embed + (size_t)row * Dc + lane * 8;
  float v[8];
  {
    float4 a = *(const float4*)e;
    float4 b = *(const float4*)(e + 4);
    v[0]=a.x; v[1]=a.y; v[2]=a.z; v[3]=a.w;
    v[4]=b.x; v[5]=b.y; v[6]=b.z; v[7]=b.w;
  }
  float p = v[0];
  #pragma unroll
  for (int j=1;j<8;++j) p *= v[j];
  float incl = p;
  #pragma unroll
  for (int off=1; off<64; off<<=1) {
    float t = __shfl_up(incl, off);
    if (lane >= off) incl *= t;
  }
  float excl = __shfl_up(incl, 1);
  if (lane == 0) excl = 1.0f;
  float c = excl;
  float o[8];
  #pragma unroll
  for (int j=0;j<8;++j) { c *= v[j]; o[j] = tanhf(c); }
  float* dst = th + (size_t)token * Dc + lane * 8;
  *(float4*)dst     = make_float4(o[0],o[1],o[2],o[3]);
  *(float4*)(dst+4) = make_float4(o[4],o[5],o[6],o[7]);
}

// ---------- chunk partial sums over time ----------
__global__ __launch_bounds__(512) void part_sums(
    const float* __restrict__ src, float* __restrict__ part)
{
  int c = blockIdx.x, b = blockIdx.y, d = threadIdx.x;
  const float* p = src + ((size_t)b * Tc + c * TS) * Dc + d;
  float s = 0.f;
  for (int t=0;t<TS;++t) s += p[(size_t)t*Dc];
  part[((size_t)b*NC + c)*Dc + d] = s;
}

// ---------- bd = cumsum_t(th); h = embed[x]*(1+bd) ----------
__global__ __launch_bounds__(512) void bd_apply(
    const float* __restrict__ th, const float* __restrict__ part,
    const int* __restrict__ x, const float* __restrict__ embed,
    float* __restrict__ h)
{
  int c = blockIdx.x, b = blockIdx.y, d = threadIdx.x;
  float acc = 0.f;
  for (int cc=0; cc<c; ++cc) acc += part[((size_t)b*NC+cc)*Dc + d];
  for (int t=0;t<TS;++t) {
    int tt = c*TS + t;
    size_t idx = ((size_t)b*Tc + tt)*Dc + d;
    acc += th[idx];
    int row = x[b*Tc + tt];
    float e = embed[(size_t)row*Dc + d];
    h[idx] = e * (1.0f + acc);
  }
}

// ---------- magsq[b,t] = ||cumsum_t(h) - h_prev||^2 (one sync total) ----------
__global__ __launch_bounds__(512) void hcum_mag(
    const float* __restrict__ h, const float* __restrict__ part,
    float* __restrict__ magsq)
{
  __shared__ float sq[8][TS];
  int c = blockIdx.x, b = blockIdx.y, d = threadIdx.x;
  int lane = d & 63, wv = d >> 6;
  float acc = 0.f;
  for (int cc=0; cc<c; ++cc) acc += part[((size_t)b*NC+cc)*Dc + d];
  for (int t=0;t<TS;++t) {
    int tt = c*TS + t;
    size_t idx = ((size_t)b*Tc + tt)*Dc + d;
    acc += h[idx];
    float hp = (tt > 0) ? h[idx - Dc] : 0.f;
    float diff = acc - hp;
    float s = diff * diff;
    #pragma unroll
    for (int off=32; off; off>>=1) s += __shfl_down(s, off);
    if (!lane) sq[wv][t] = s;
  }
  __syncthreads();
  if (d < TS) {
    float s = 0.f;
    #pragma unroll
    for (int w2=0;w2<8;++w2) s += sq[w2][d];
    magsq[b*Tc + c*TS + d] = s;
  }
}

// ---------- geometric scan: ctx = sqrt(magsq) * |S| ----------
__global__ __launch_bounds__(512) void scan_ctx(
    const float* __restrict__ h, const float* __restrict__ magsq,
    const float* __restrict__ kvec, int l, float* __restrict__ ctx)
{
  int c = blockIdx.x, b = blockIdx.y, d = threadIdx.x;
  float kk = kvec[l];
  float sp = kk > 0.f ? kk + log1pf(expf(-kk)) : log1pf(expf(kk));
  float w = expf(-sp);
  int t0 = c * TS;
  int ts = t0 - WARM; if (ts < 0) ts = 0;
  float s = 0.f;
  for (int t=ts; t<t0; ++t) s = h[((size_t)b*Tc + t)*Dc + d] + w*s;
  for (int t=t0; t<t0+TS; ++t) {
    size_t idx = ((size_t)b*Tc + t)*Dc + d;
    s = h[idx] + w * s;
    ctx[idx] = sqrtf(magsq[b*Tc + t]) * fabsf(s);
  }
}

// ---------- layernorm -> bf16 (eps=1e-3) ----------
__global__ __launch_bounds__(256) void ln_bf16(
    const float* __restrict__ y, const float* __restrict__ g,
    const float* __restrict__ bt, int l, unsigned short* __restrict__ yb)
{
  __shared__ float red[4];
  int token = blockIdx.x, tid = threadIdx.x;
  int lane = tid & 63, wv = tid >> 6;
  const float* p = y + (size_t)token * Dc;
  float x0 = p[tid], x1 = p[tid + 256];
  float s = x0 + x1;
  #pragma unroll
  for (int off=32; off; off>>=1) s += __shfl_down(s, off);
  if (!lane) red[wv] = s;
  __syncthreads();
  float mu = (red[0]+red[1]+red[2]+red[3]) * (1.f/Dc);
  float d0 = x0 - mu, d1 = x1 - mu;
  float s2 = d0*d0 + d1*d1;
  __syncthreads();
  #pragma unroll
  for (int off=32; off; off>>=1) s2 += __shfl_down(s2, off);
  if (!lane) red[wv] = s2;
  __syncthreads();
  float var = (red[0]+red[1]+red[2]+red[3]) * (1.f/Dc);
  float rs = rsqrtf(var + 1e-3f);
  yb[(size_t)token*Dc + tid]       = f2bf(d0 * rs * g[l*Dc + tid]       + bt[l*Dc + tid]);
  yb[(size_t)token*Dc + tid + 256] = f2bf(d1 * rs * g[l*Dc + tid + 256] + bt[l*Dc + tid + 256]);
}

// ---------- W (L,R,C) fp32 -> Wt (L,C,R) bf16 ----------
__global__ __launch_bounds__(256) void transpose_to_bf16(
    const float* __restrict__ W, unsigned short* __restrict__ Wt, int R, int C)
{
  __shared__ float tile[32][33];
  int l = blockIdx.z;
  const float* Wl = W + (size_t)l * R * C;
  unsigned short* Wtl = Wt + (size_t)l * R * C;
  int c0 = blockIdx.x * 32, r0 = blockIdx.y * 32;
  int tx = threadIdx.x & 31, ty = threadIdx.x >> 5;
  for (int i = ty; i < 32; i += 8)
    tile[i][tx] = Wl[(size_t)(r0+i)*C + (c0+tx)];
  __syncthreads();
  for (int i = ty; i < 32; i += 8)
    Wtl[(size_t)(c0+i)*R + (r0+tx)] = f2bf(tile[tx][i]);
}

__global__ __launch_bounds__(256) void conv_bf16(
    const float* __restrict__ src, unsigned short* __restrict__ dst, int n)
{
  int i = blockIdx.x * 256 + threadIdx.x;
  if (i < n) dst[i] = f2bf(src[i]);
}

// ---------- bf16 MFMA GEMM: 128x128 tile, 4 waves, 4x4 16x16 tiles/wave ----
// A: MxK bf16 row-major. Bt: NxK bf16 row-major. C = A @ Bt^T.
// LDS tiles 128x32 bf16, 16B-chunk XOR swizzle c' = c ^ ((row&3)^((row>>3)&1))
// -> staging via global_load_lds (lane-ordered) and ds_read_b128 both 2-way.
// EPI 0: Cb = bf16(gelu(z+bias));  1: C += z+bias, Cb = bf16(C);  2: C = z.
template<int EPI>
__global__ __launch_bounds__(256) void mgemm(
    const unsigned short* __restrict__ A,
    const unsigned short* __restrict__ Bt,
    const float* __restrict__ bias,
    float* __restrict__ C, unsigned short* __restrict__ Cb,
    int N, int K)
{
  __shared__ unsigned short As[128*32];
  __shared__ unsigned short Bs[128*32];
  int tid = threadIdx.x;
  int lane = tid & 63, w = tid >> 6;
  int wr = w >> 1, wc = w & 1;
  int m0 = blockIdx.y * 128, n0 = blockIdx.x * 128;

  // staging: pass p covers chunk ci = p*256 + tid; row=ci>>2, c'=ci&3
  const unsigned short* ag[2];
  const unsigned short* bg[2];
  #pragma unroll
  for (int p=0;p<2;++p) {
    int ci = p*256 + tid;
    int row = ci >> 2, cp = ci & 3;
    int cg = cp ^ ((row & 3) ^ ((row >> 3) & 1));
    ag[p] = A  + (size_t)(m0+row)*K + cg*8;
    bg[p] = Bt + (size_t)(n0+row)*K + cg*8;
  }
  unsigned short* asw[2] = { &As[w*512], &As[2048 + w*512] };
  unsigned short* bsw[2] = { &Bs[w*512], &Bs[2048 + w*512] };

  int r = lane & 15, quad = lane >> 4;
  int cidx = quad ^ ((r & 3) ^ ((r >> 3) & 1));
  int aoff[4], boff[4];
  #pragma unroll
  for (int i=0;i<4;++i) {
    aoff[i] = (wr*64 + i*16 + r)*32 + cidx*8;
    boff[i] = (wc*64 + i*16 + r)*32 + cidx*8;
  }

  f32x4 acc[4][4];
  #pragma unroll
  for (int i=0;i<4;++i)
    #pragma unroll
    for (int j=0;j<4;++j)
      acc[i][j] = (f32x4){0.f,0.f,0.f,0.f};

  for (int k0 = 0; k0 < K; k0 += 32) {
    #pragma unroll
    for (int p=0;p<2;++p) {
      gload_lds16(ag[p] + k0, asw[p]);
      gload_lds16(bg[p] + k0, bsw[p]);
    }
    __syncthreads();
    short8 af[4], bfr[4];
    #pragma unroll
    for (int i=0;i<4;++i) {
      af[i]  = *(const short8*)&As[aoff[i]];
      bfr[i] = *(const short8*)&Bs[boff[i]];
    }
    #pragma unroll
    for (int i=0;i<4;++i)
      #pragma unroll
      for (int j=0;j<4;++j)
        acc[i][j] = __builtin_amdgcn_mfma_f32_16x16x32_bf16(af[i], bfr[j], acc[i][j], 0, 0, 0);
    __syncthreads();
  }

  #pragma unroll
  for (int i=0;i<4;++i) {
    int rowb = m0 + wr*64 + i*16 + quad*4;
    #pragma unroll
    for (int j=0;j<4;++j) {
      int col = n0 + wc*64 + j*16 + r;
      float bv = 0.f;
      if (EPI != 2) bv = bias[col];
      #pragma unroll
      for (int reg=0;reg<4;++reg) {
        size_t idx = (size_t)(rowb + reg) * N + col;
        float z = acc[i][j][reg] + bv;
        if (EPI == 0) {
          z = 0.5f * z * (1.0f + erff(z * 0.707106781186547524f));
          Cb[idx] = f2bf(z);
        } else if (EPI == 1) {
          float hv = C[idx] + z;
          C[idx] = hv;
          Cb[idx] = f2bf(hv);
        } else {
          C[idx] = z;
        }
      }
    }
  }
}

extern "C" void kernel_launch(void* const* d_in, const int* in_sizes, int n_in,
                              void* d_out, int out_size, void* d_ws, size_t ws_size,
                              hipStream_t stream) {
  const int*   x     = (const int*)  d_in[0];
  const float* embed = (const float*)d_in[1];
  const float* kvec  = (const float*)d_in[2];
  const float* g     = (const float*)d_in[3];
  const float* bt    = (const float*)d_in[4];
  const float* W1    = (const float*)d_in[5];
  const float* b1    = (const float*)d_in[6];
  const float* W2    = (const float*)d_in[7];
  const float* b2    = (const float*)d_in[8];
  float* out = (float*)d_out;

  const size_t NTD = (size_t)Bc * Tc * Dc;   // 4,194,304
  const size_t NTH = (size_t)Bc * Tc * Hc;   // 16,777,216
  char* wsb = (char*)d_ws;
  float* h      = (float*)wsb;                wsb += NTD*4;            // 16MB
  float* tmpA   = (float*)wsb;                wsb += NTD*4;            // 16MB
  float* part   = (float*)wsb;                wsb += (size_t)Bc*NC*Dc*4;
  float* magsq  = (float*)wsb;                wsb += (size_t)Bc*Tc*4;
  unsigned short* yb   = (unsigned short*)wsb; wsb += NTD*2;           // 8MB
  unsigned short* a1b  = (unsigned short*)wsb; wsb += NTH*2;           // 32MB
  unsigned short* hb   = (unsigned short*)wsb; wsb += NTD*2;           // 8MB
  unsigned short* W1t  = (unsigned short*)wsb; wsb += (size_t)3*Dc*Hc*2; // 6MB
  unsigned short* W2t  = (unsigned short*)wsb; wsb += (size_t)3*Dc*Hc*2; // 6MB
  unsigned short* emb  = (unsigned short*)wsb; wsb += (size_t)Vc*Dc*2;

  // weight prep (per call; ~15us)
  transpose_to_bf16<<<dim3(Hc/32, Dc/32, 3), 256, 0, stream>>>(W1, W1t, Dc, Hc);
  transpose_to_bf16<<<dim3(Dc/32, Hc/32, 3), 256, 0, stream>>>(W2, W2t, Hc, Dc);
  conv_bf16<<<dim3(Vc*Dc/256), 256, 0, stream>>>(embed, emb, Vc*Dc);

  // prologue
  embed_boundary<<<dim3(Bc*Tc/4), 256, 0, stream>>>(x, embed, tmpA);
  part_sums<<<dim3(NC, Bc), 512, 0, stream>>>(tmpA, part);
  bd_apply<<<dim3(NC, Bc), 512, 0, stream>>>(tmpA, part, x, embed, h);

  for (int l = 0; l < 3; ++l) {
    part_sums<<<dim3(NC, Bc), 512, 0, stream>>>(h, part);
    hcum_mag<<<dim3(NC, Bc), 512, 0, stream>>>(h, part, magsq);
    scan_ctx<<<dim3(NC, Bc), 512, 0, stream>>>(h, magsq, kvec, l, tmpA);
    ln_bf16<<<dim3(Bc*Tc), 256, 0, stream>>>(tmpA, g, bt, l, yb);
    // z = gelu(y @ W1 + b1): M=8192 N=2048 K=512 -> a1b (bf16)
    mgemm<0><<<dim3(Hc/128, Bc*Tc/128), 256, 0, stream>>>(
        yb, W1t + (size_t)l*Hc*Dc, b1 + (size_t)l*Hc, nullptr, a1b, Hc, Dc);
    // h += z @ W2 + b2: M=8192 N=512 K=2048; also hb = bf16(h)
    mgemm<1><<<dim3(Dc/128, Bc*Tc/128), 256, 0, stream>>>(
        a1b, W2t + (size_t)l*Dc*Hc, b2 + (size_t)l*Dc, h, hb, Dc, Hc);
  }
  // out = h @ embed^T: M=8192 N=256 K=512
  mgemm<2><<<dim3(Vc/128, Bc*Tc/128), 256, 0, stream>>>(
      hb, emb, nullptr, out, nullptr, Vc, Dc);
}

// Round 3
// 593.066 us; speedup vs baseline: 3.4970x; 1.1412x over previous
//
#include <hip/hip_runtime.h>
#include <math.h>

// DeltaLM: B=4 T=2048 D=512 H=2048 L=3 V=256
// decay einsum == geometric scan S[i]=h[i]+w*S[i-1], w=exp(-softplus(k)),
// w^32~6e-19 -> 32-step warmup chunked scan is exact in fp32.
// Round 3: scan-shaped kernels re-chunked 128->32 steps (64 -> 256 blocks;
// R2 showed 4.9% occupancy / 1.6% VALUBusy = latency wall), hcum_mag+scan_ctx
// fused (h cached in regs, magsq never leaves LDS, h[t-1] kept in register).

constexpr int Bc = 4, Tc = 2048, Dc = 512, Hc = 2048, Vc = 256;
constexpr int TSF = 32, NCF = 64, WARM = 32;   // fine time chunks: 64 x 32

typedef __attribute__((ext_vector_type(8))) short short8;
typedef __attribute__((ext_vector_type(4))) float f32x4;

__device__ inline unsigned short f2bf(float f) {  // RNE fp32->bf16
  unsigned int u = __float_as_uint(f);
  u += 0x7fffu + ((u >> 16) & 1u);
  return (unsigned short)(u >> 16);
}

__device__ inline void gload_lds16(const void* g, void* l) {
  __builtin_amdgcn_global_load_lds(
      (const __attribute__((address_space(1))) void*)g,
      (__attribute__((address_space(3))) void*)l, 16, 0, 0);
}

// ---------- embed gather + cumprod(feature) + tanh ----------
__global__ __launch_bounds__(256) void embed_boundary(
    const int* __restrict__ x, const float* __restrict__ embed,
    float* __restrict__ th)
{
  int token = blockIdx.x * 4 + (threadIdx.x >> 6);
  int lane  = threadIdx.x & 63;
  int row = x[token];
  const float* e = embed + (size_t)row * Dc + lane * 8;
  float v[8];
  {
    float4 a = *(const float4*)e;
    float4 b = *(const float4*)(e + 4);
    v[0]=a.x; v[1]=a.y; v[2]=a.z; v[3]=a.w;
    v[4]=b.x; v[5]=b.y; v[6]=b.z; v[7]=b.w;
  }
  float p = v[0];
  #pragma unroll
  for (int j=1;j<8;++j) p *= v[j];
  float incl = p;
  #pragma unroll
  for (int off=1; off<64; off<<=1) {
    float t = __shfl_up(incl, off);
    if (lane >= off) incl *= t;
  }
  float excl = __shfl_up(incl, 1);
  if (lane == 0) excl = 1.0f;
  float c = excl;
  float o[8];
  #pragma unroll
  for (int j=0;j<8;++j) { c *= v[j]; o[j] = tanhf(c); }
  float* dst = th + (size_t)token * Dc + lane * 8;
  *(float4*)dst     = make_float4(o[0],o[1],o[2],o[3]);
  *(float4*)(dst+4) = make_float4(o[4],o[5],o[6],o[7]);
}

// ---------- chunk partial sums over time (fine: 32 steps, 256 blocks) ------
__global__ __launch_bounds__(512) void part_sums(
    const float* __restrict__ src, float* __restrict__ part)
{
  int c = blockIdx.x, b = blockIdx.y, d = threadIdx.x;
  const float* p = src + ((size_t)b * Tc + c * TSF) * Dc + d;
  float s = 0.f;
  #pragma unroll
  for (int t=0;t<TSF;++t) s += p[(size_t)t*Dc];
  part[((size_t)b*NCF + c)*Dc + d] = s;
}

// ---------- bd = cumsum_t(th); h = embed[x]*(1+bd) ----------
__global__ __launch_bounds__(512) void bd_apply(
    const float* __restrict__ th, const float* __restrict__ part,
    const int* __restrict__ x, const float* __restrict__ embed,
    float* __restrict__ h)
{
  int c = blockIdx.x, b = blockIdx.y, d = threadIdx.x;
  float acc = 0.f;
  for (int cc=0; cc<c; ++cc) acc += part[((size_t)b*NCF+cc)*Dc + d];
  #pragma unroll
  for (int t=0;t<TSF;++t) {
    int tt = c*TSF + t;
    size_t idx = ((size_t)b*Tc + tt)*Dc + d;
    acc += th[idx];
    int row = x[b*Tc + tt];
    float e = embed[(size_t)row*Dc + d];
    h[idx] = e * (1.0f + acc);
  }
}

// ---------- fused: magsq (LDS only) + geometric scan -> ctx ----------
// mag[t] = ||cumsum(h)[t] - h[t-1]||; ctx[t,d] = mag[t] * |S[t,d]|,
// S = h + w*S_prev with 32-step warmup (exact: w <= sigmoid(-k), w^32 ~ 1e-18)
__global__ __launch_bounds__(512) void mag_scan(
    const float* __restrict__ h, const float* __restrict__ part,
    const float* __restrict__ kvec, int l, float* __restrict__ ctx)
{
  __shared__ float red[8][TSF];
  __shared__ float mag[TSF];
  int c = blockIdx.x, b = blockIdx.y, d = threadIdx.x;
  int lane = d & 63, wv = d >> 6;
  float acc = 0.f;
  for (int cc=0; cc<c; ++cc) acc += part[((size_t)b*NCF+cc)*Dc + d];
  int t0 = c * TSF;
  const float* hbase = h + (size_t)b*Tc*Dc + d;
  float hp = (t0 > 0) ? hbase[(size_t)(t0-1)*Dc] : 0.f;
  float hv[TSF];
  #pragma unroll
  for (int t=0;t<TSF;++t) {
    hv[t] = hbase[(size_t)(t0+t)*Dc];
    acc += hv[t];
    float diff = acc - hp;
    hp = hv[t];
    float s = diff * diff;
    #pragma unroll
    for (int off=32; off; off>>=1) s += __shfl_down(s, off);
    if (!lane) red[wv][t] = s;
  }
  // geometric warmup (independent of the reduction finalize)
  float kk = kvec[l];
  float sp = kk > 0.f ? kk + log1pf(expf(-kk)) : log1pf(expf(kk));
  float w = expf(-sp);
  int ts = t0 - WARM; if (ts < 0) ts = 0;
  float s = 0.f;
  for (int t=ts; t<t0; ++t) s = hbase[(size_t)t*Dc] + w*s;
  __syncthreads();
  if (d < TSF) {
    float m = 0.f;
    #pragma unroll
    for (int w2=0;w2<8;++w2) m += red[w2][d];
    mag[d] = sqrtf(m);
  }
  __syncthreads();
  float* cbase = ctx + (size_t)b*Tc*Dc + d;
  #pragma unroll
  for (int t=0;t<TSF;++t) {
    s = hv[t] + w * s;
    cbase[(size_t)(t0+t)*Dc] = mag[t] * fabsf(s);
  }
}

// ---------- layernorm -> bf16 (eps=1e-3) ----------
__global__ __launch_bounds__(256) void ln_bf16(
    const float* __restrict__ y, const float* __restrict__ g,
    const float* __restrict__ bt, int l, unsigned short* __restrict__ yb)
{
  __shared__ float red[4];
  int token = blockIdx.x, tid = threadIdx.x;
  int lane = tid & 63, wv = tid >> 6;
  const float* p = y + (size_t)token * Dc;
  float x0 = p[tid], x1 = p[tid + 256];
  float s = x0 + x1;
  #pragma unroll
  for (int off=32; off; off>>=1) s += __shfl_down(s, off);
  if (!lane) red[wv] = s;
  __syncthreads();
  float mu = (red[0]+red[1]+red[2]+red[3]) * (1.f/Dc);
  float d0 = x0 - mu, d1 = x1 - mu;
  float s2 = d0*d0 + d1*d1;
  __syncthreads();
  #pragma unroll
  for (int off=32; off; off>>=1) s2 += __shfl_down(s2, off);
  if (!lane) red[wv] = s2;
  __syncthreads();
  float var = (red[0]+red[1]+red[2]+red[3]) * (1.f/Dc);
  float rs = rsqrtf(var + 1e-3f);
  yb[(size_t)token*Dc + tid]       = f2bf(d0 * rs * g[l*Dc + tid]       + bt[l*Dc + tid]);
  yb[(size_t)token*Dc + tid + 256] = f2bf(d1 * rs * g[l*Dc + tid + 256] + bt[l*Dc + tid + 256]);
}

// ---------- W (L,R,C) fp32 -> Wt (L,C,R) bf16 ----------
__global__ __launch_bounds__(256) void transpose_to_bf16(
    const float* __restrict__ W, unsigned short* __restrict__ Wt, int R, int C)
{
  __shared__ float tile[32][33];
  int l = blockIdx.z;
  const float* Wl = W + (size_t)l * R * C;
  unsigned short* Wtl = Wt + (size_t)l * R * C;
  int c0 = blockIdx.x * 32, r0 = blockIdx.y * 32;
  int tx = threadIdx.x & 31, ty = threadIdx.x >> 5;
  for (int i = ty; i < 32; i += 8)
    tile[i][tx] = Wl[(size_t)(r0+i)*C + (c0+tx)];
  __syncthreads();
  for (int i = ty; i < 32; i += 8)
    Wtl[(size_t)(c0+i)*R + (r0+tx)] = f2bf(tile[tx][i]);
}

__global__ __launch_bounds__(256) void conv_bf16(
    const float* __restrict__ src, unsigned short* __restrict__ dst, int n)
{
  int i = blockIdx.x * 256 + threadIdx.x;
  if (i < n) dst[i] = f2bf(src[i]);
}

// ---------- bf16 MFMA GEMM: 128x128 tile, 4 waves, 4x4 16x16 tiles/wave ----
// A: MxK bf16 row-major. Bt: NxK bf16 row-major. C = A @ Bt^T.
// LDS tiles 128x32 bf16, 16B-chunk XOR swizzle c' = c ^ ((row&3)^((row>>3)&1))
// EPI 0: Cb = bf16(gelu(z+bias));  1: C += z+bias, Cb = bf16(C);  2: C = z.
template<int EPI>
__global__ __launch_bounds__(256) void mgemm(
    const unsigned short* __restrict__ A,
    const unsigned short* __restrict__ Bt,
    const float* __restrict__ bias,
    float* __restrict__ C, unsigned short* __restrict__ Cb,
    int N, int K)
{
  __shared__ unsigned short As[128*32];
  __shared__ unsigned short Bs[128*32];
  int tid = threadIdx.x;
  int lane = tid & 63, w = tid >> 6;
  int wr = w >> 1, wc = w & 1;
  int m0 = blockIdx.y * 128, n0 = blockIdx.x * 128;

  const unsigned short* ag[2];
  const unsigned short* bg[2];
  #pragma unroll
  for (int p=0;p<2;++p) {
    int ci = p*256 + tid;
    int row = ci >> 2, cp = ci & 3;
    int cg = cp ^ ((row & 3) ^ ((row >> 3) & 1));
    ag[p] = A  + (size_t)(m0+row)*K + cg*8;
    bg[p] = Bt + (size_t)(n0+row)*K + cg*8;
  }
  unsigned short* asw[2] = { &As[w*512], &As[2048 + w*512] };
  unsigned short* bsw[2] = { &Bs[w*512], &Bs[2048 + w*512] };

  int r = lane & 15, quad = lane >> 4;
  int cidx = quad ^ ((r & 3) ^ ((r >> 3) & 1));
  int aoff[4], boff[4];
  #pragma unroll
  for (int i=0;i<4;++i) {
    aoff[i] = (wr*64 + i*16 + r)*32 + cidx*8;
    boff[i] = (wc*64 + i*16 + r)*32 + cidx*8;
  }

  f32x4 acc[4][4];
  #pragma unroll
  for (int i=0;i<4;++i)
    #pragma unroll
    for (int j=0;j<4;++j)
      acc[i][j] = (f32x4){0.f,0.f,0.f,0.f};

  for (int k0 = 0; k0 < K; k0 += 32) {
    #pragma unroll
    for (int p=0;p<2;++p) {
      gload_lds16(ag[p] + k0, asw[p]);
      gload_lds16(bg[p] + k0, bsw[p]);
    }
    __syncthreads();
    short8 af[4], bfr[4];
    #pragma unroll
    for (int i=0;i<4;++i) {
      af[i]  = *(const short8*)&As[aoff[i]];
      bfr[i] = *(const short8*)&Bs[boff[i]];
    }
    #pragma unroll
    for (int i=0;i<4;++i)
      #pragma unroll
      for (int j=0;j<4;++j)
        acc[i][j] = __builtin_amdgcn_mfma_f32_16x16x32_bf16(af[i], bfr[j], acc[i][j], 0, 0, 0);
    __syncthreads();
  }

  #pragma unroll
  for (int i=0;i<4;++i) {
    int rowb = m0 + wr*64 + i*16 + quad*4;
    #pragma unroll
    for (int j=0;j<4;++j) {
      int col = n0 + wc*64 + j*16 + r;
      float bv = 0.f;
      if (EPI != 2) bv = bias[col];
      #pragma unroll
      for (int reg=0;reg<4;++reg) {
        size_t idx = (size_t)(rowb + reg) * N + col;
        float z = acc[i][j][reg] + bv;
        if (EPI == 0) {
          z = 0.5f * z * (1.0f + erff(z * 0.707106781186547524f));
          Cb[idx] = f2bf(z);
        } else if (EPI == 1) {
          float hv = C[idx] + z;
          C[idx] = hv;
          Cb[idx] = f2bf(hv);
        } else {
          C[idx] = z;
        }
      }
    }
  }
}

extern "C" void kernel_launch(void* const* d_in, const int* in_sizes, int n_in,
                              void* d_out, int out_size, void* d_ws, size_t ws_size,
                              hipStream_t stream) {
  const int*   x     = (const int*)  d_in[0];
  const float* embed = (const float*)d_in[1];
  const float* kvec  = (const float*)d_in[2];
  const float* g     = (const float*)d_in[3];
  const float* bt    = (const float*)d_in[4];
  const float* W1    = (const float*)d_in[5];
  const float* b1    = (const float*)d_in[6];
  const float* W2    = (const float*)d_in[7];
  const float* b2    = (const float*)d_in[8];
  float* out = (float*)d_out;

  const size_t NTD = (size_t)Bc * Tc * Dc;   // 4,194,304
  const size_t NTH = (size_t)Bc * Tc * Hc;   // 16,777,216
  char* wsb = (char*)d_ws;
  float* h      = (float*)wsb;                wsb += NTD*4;              // 16MB
  float* tmpA   = (float*)wsb;                wsb += NTD*4;              // 16MB
  float* part   = (float*)wsb;                wsb += (size_t)Bc*NCF*Dc*4; // 512KB
  unsigned short* yb   = (unsigned short*)wsb; wsb += NTD*2;             // 8MB
  unsigned short* a1b  = (unsigned short*)wsb; wsb += NTH*2;             // 32MB
  unsigned short* hb   = (unsigned short*)wsb; wsb += NTD*2;             // 8MB
  unsigned short* W1t  = (unsigned short*)wsb; wsb += (size_t)3*Dc*Hc*2; // 6MB
  unsigned short* W2t  = (unsigned short*)wsb; wsb += (size_t)3*Dc*Hc*2; // 6MB
  unsigned short* emb  = (unsigned short*)wsb; wsb += (size_t)Vc*Dc*2;

  // weight prep (per call)
  transpose_to_bf16<<<dim3(Hc/32, Dc/32, 3), 256, 0, stream>>>(W1, W1t, Dc, Hc);
  transpose_to_bf16<<<dim3(Dc/32, Hc/32, 3), 256, 0, stream>>>(W2, W2t, Hc, Dc);
  conv_bf16<<<dim3(Vc*Dc/256), 256, 0, stream>>>(embed, emb, Vc*Dc);

  // prologue
  embed_boundary<<<dim3(Bc*Tc/4), 256, 0, stream>>>(x, embed, tmpA);
  part_sums<<<dim3(NCF, Bc), 512, 0, stream>>>(tmpA, part);
  bd_apply<<<dim3(NCF, Bc), 512, 0, stream>>>(tmpA, part, x, embed, h);

  for (int l = 0; l < 3; ++l) {
    part_sums<<<dim3(NCF, Bc), 512, 0, stream>>>(h, part);
    mag_scan<<<dim3(NCF, Bc), 512, 0, stream>>>(h, part, kvec, l, tmpA);
    ln_bf16<<<dim3(Bc*Tc), 256, 0, stream>>>(tmpA, g, bt, l, yb);
    // z = gelu(y @ W1 + b1): M=8192 N=2048 K=512 -> a1b (bf16)
    mgemm<0><<<dim3(Hc/128, Bc*Tc/128), 256, 0, stream>>>(
        yb, W1t + (size_t)l*Hc*Dc, b1 + (size_t)l*Hc, nullptr, a1b, Hc, Dc);
    // h += z @ W2 + b2: M=8192 N=512 K=2048; also hb = bf16(h)
    mgemm<1><<<dim3(Dc/128, Bc*Tc/128), 256, 0, stream>>>(
        a1b, W2t + (size_t)l*Dc*Hc, b2 + (size_t)l*Dc, h, hb, Dc, Hc);
  }
  // out = h @ embed^T: M=8192 N=256 K=512
  mgemm<2><<<dim3(Vc/128, Bc*Tc/128), 256, 0, stream>>>(
      hb, emb, nullptr, out, nullptr, Vc, Dc);
}

// Round 4
// 557.748 us; speedup vs baseline: 3.7185x; 1.0633x over previous
//
#include <hip/hip_runtime.h>
#include <math.h>

// DeltaLM: B=4 T=2048 D=512 H=2048 L=3 V=256
// decay einsum == geometric scan S[i]=h[i]+w*S[i-1], w=exp(-softplus(k)),
// w^32~6e-19 -> 32-step warmup chunked scan is exact in fp32.
// Round 4: (1) mgemm<1> was 1 block/CU (MfmaUtil 10%) -> TN=64 tile = 512
// blocks = 2/CU; (2) double-buffered LDS, ONE barrier per K-step, prefetch
// issued right after the barrier overlaps load latency with MFMA+ds_read;
// (3) LN fused into mag_scan (ctx never hits HBM, -32MB/layer, -3 launches).

constexpr int Bc = 4, Tc = 2048, Dc = 512, Hc = 2048, Vc = 256;
constexpr int TSF = 32, NCF = 64, WARM = 32;   // fine time chunks: 64 x 32

typedef __attribute__((ext_vector_type(8))) short short8;
typedef __attribute__((ext_vector_type(4))) float f32x4;

__device__ inline unsigned short f2bf(float f) {  // RNE fp32->bf16
  unsigned int u = __float_as_uint(f);
  u += 0x7fffu + ((u >> 16) & 1u);
  return (unsigned short)(u >> 16);
}

__device__ inline void gload_lds16(const void* g, void* l) {
  __builtin_amdgcn_global_load_lds(
      (const __attribute__((address_space(1))) void*)g,
      (__attribute__((address_space(3))) void*)l, 16, 0, 0);
}

// ---------- embed gather + cumprod(feature) + tanh ----------
__global__ __launch_bounds__(256) void embed_boundary(
    const int* __restrict__ x, const float* __restrict__ embed,
    float* __restrict__ th)
{
  int token = blockIdx.x * 4 + (threadIdx.x >> 6);
  int lane  = threadIdx.x & 63;
  int row = x[token];
  const float* e = embed + (size_t)row * Dc + lane * 8;
  float v[8];
  {
    float4 a = *(const float4*)e;
    float4 b = *(const float4*)(e + 4);
    v[0]=a.x; v[1]=a.y; v[2]=a.z; v[3]=a.w;
    v[4]=b.x; v[5]=b.y; v[6]=b.z; v[7]=b.w;
  }
  float p = v[0];
  #pragma unroll
  for (int j=1;j<8;++j) p *= v[j];
  float incl = p;
  #pragma unroll
  for (int off=1; off<64; off<<=1) {
    float t = __shfl_up(incl, off);
    if (lane >= off) incl *= t;
  }
  float excl = __shfl_up(incl, 1);
  if (lane == 0) excl = 1.0f;
  float c = excl;
  float o[8];
  #pragma unroll
  for (int j=0;j<8;++j) { c *= v[j]; o[j] = tanhf(c); }
  float* dst = th + (size_t)token * Dc + lane * 8;
  *(float4*)dst     = make_float4(o[0],o[1],o[2],o[3]);
  *(float4*)(dst+4) = make_float4(o[4],o[5],o[6],o[7]);
}

// ---------- chunk partial sums over time ----------
__global__ __launch_bounds__(512) void part_sums(
    const float* __restrict__ src, float* __restrict__ part)
{
  int c = blockIdx.x, b = blockIdx.y, d = threadIdx.x;
  const float* p = src + ((size_t)b * Tc + c * TSF) * Dc + d;
  float s = 0.f;
  #pragma unroll
  for (int t=0;t<TSF;++t) s += p[(size_t)t*Dc];
  part[((size_t)b*NCF + c)*Dc + d] = s;
}

// ---------- bd = cumsum_t(th); h = embed[x]*(1+bd) ----------
__global__ __launch_bounds__(512) void bd_apply(
    const float* __restrict__ th, const float* __restrict__ part,
    const int* __restrict__ x, const float* __restrict__ embed,
    float* __restrict__ h)
{
  int c = blockIdx.x, b = blockIdx.y, d = threadIdx.x;
  float acc = 0.f;
  for (int cc=0; cc<c; ++cc) acc += part[((size_t)b*NCF+cc)*Dc + d];
  #pragma unroll
  for (int t=0;t<TSF;++t) {
    int tt = c*TSF + t;
    size_t idx = ((size_t)b*Tc + tt)*Dc + d;
    acc += th[idx];
    int row = x[b*Tc + tt];
    float e = embed[(size_t)row*Dc + d];
    h[idx] = e * (1.0f + acc);
  }
}

// ---------- fused: mag (LDS only) + geometric scan + LayerNorm -> bf16 ----
// mag[t]=||cumsum(h)[t]-h[t-1]||; ctx=mag*|S|, S=h+w*S_prev (32-step warmup);
// y = LN(ctx)*g+b cast to bf16. ctx lives entirely in registers.
__global__ __launch_bounds__(512) void mag_scan_ln(
    const float* __restrict__ h, const float* __restrict__ part,
    const float* __restrict__ kvec, int l,
    const float* __restrict__ g, const float* __restrict__ bt,
    unsigned short* __restrict__ yb)
{
  __shared__ float redA[8][TSF];
  __shared__ float redB[8][TSF];
  __shared__ float mag[TSF], muS[TSF], rsS[TSF];
  int c = blockIdx.x, b = blockIdx.y, d = threadIdx.x;
  int lane = d & 63, wv = d >> 6;
  float acc = 0.f;
  for (int cc=0; cc<c; ++cc) acc += part[((size_t)b*NCF+cc)*Dc + d];
  int t0 = c * TSF;
  const float* hbase = h + (size_t)b*Tc*Dc + d;
  float hp = (t0 > 0) ? hbase[(size_t)(t0-1)*Dc] : 0.f;
  float hv[TSF];
  #pragma unroll
  for (int t=0;t<TSF;++t) {
    hv[t] = hbase[(size_t)(t0+t)*Dc];
    acc += hv[t];
    float diff = acc - hp;
    hp = hv[t];
    float s = diff * diff;
    #pragma unroll
    for (int off=32; off; off>>=1) s += __shfl_down(s, off);
    if (!lane) redA[wv][t] = s;
  }
  // geometric warmup (independent of the reduction finalize)
  float kk = kvec[l];
  float sp = kk > 0.f ? kk + log1pf(expf(-kk)) : log1pf(expf(kk));
  float w = expf(-sp);
  int ts = t0 - WARM; if (ts < 0) ts = 0;
  float s = 0.f;
  for (int t=ts; t<t0; ++t) s = hbase[(size_t)t*Dc] + w*s;
  __syncthreads();
  if (d < TSF) {
    float m = 0.f;
    #pragma unroll
    for (int w2=0;w2<8;++w2) m += redA[w2][d];
    mag[d] = sqrtf(m);
  }
  __syncthreads();
  // scan + ctx (into hv) + LN partials (sum, sumsq per token)
  #pragma unroll
  for (int t=0;t<TSF;++t) {
    s = hv[t] + w * s;
    float cv = mag[t] * fabsf(s);
    hv[t] = cv;
    float s1 = cv, s2 = cv * cv;
    #pragma unroll
    for (int off=32; off; off>>=1) {
      s1 += __shfl_down(s1, off);
      s2 += __shfl_down(s2, off);
    }
    if (!lane) { redA[wv][t] = s1; redB[wv][t] = s2; }
  }
  __syncthreads();
  if (d < TSF) {
    float m1 = 0.f, m2 = 0.f;
    #pragma unroll
    for (int w2=0;w2<8;++w2) { m1 += redA[w2][d]; m2 += redB[w2][d]; }
    float mu = m1 * (1.f/Dc);
    float var = fmaxf(m2 * (1.f/Dc) - mu*mu, 0.f);
    muS[d] = mu;
    rsS[d] = rsqrtf(var + 1e-3f);
  }
  __syncthreads();
  float gv = g[l*Dc + d], bv = bt[l*Dc + d];
  unsigned short* yp = yb + ((size_t)b*Tc + t0)*Dc + d;
  #pragma unroll
  for (int t=0;t<TSF;++t)
    yp[(size_t)t*Dc] = f2bf((hv[t] - muS[t]) * rsS[t] * gv + bv);
}

// ---------- W (L,R,C) fp32 -> Wt (L,C,R) bf16 ----------
__global__ __launch_bounds__(256) void transpose_to_bf16(
    const float* __restrict__ W, unsigned short* __restrict__ Wt, int R, int C)
{
  __shared__ float tile[32][33];
  int l = blockIdx.z;
  const float* Wl = W + (size_t)l * R * C;
  unsigned short* Wtl = Wt + (size_t)l * R * C;
  int c0 = blockIdx.x * 32, r0 = blockIdx.y * 32;
  int tx = threadIdx.x & 31, ty = threadIdx.x >> 5;
  for (int i = ty; i < 32; i += 8)
    tile[i][tx] = Wl[(size_t)(r0+i)*C + (c0+tx)];
  __syncthreads();
  for (int i = ty; i < 32; i += 8)
    Wtl[(size_t)(c0+i)*R + (r0+tx)] = f2bf(tile[tx][i]);
}

__global__ __launch_bounds__(256) void conv_bf16(
    const float* __restrict__ src, unsigned short* __restrict__ dst, int n)
{
  int i = blockIdx.x * 256 + threadIdx.x;
  if (i < n) dst[i] = f2bf(src[i]);
}

// ---------- bf16 MFMA GEMM, double-buffered LDS, 1 barrier / K-step -------
// A: MxK bf16 row-major. Bt: NxK bf16 row-major. C = A @ Bt^T.
// Tile TM x TN, 4 waves in 2x2 grid, each wave (TM/2)x(TN/2) of 16x16 MFMAs.
// LDS 16B-chunk XOR swizzle c' = c ^ ((row&3)^((row>>3)&1)).
// EPI 0: Cb = bf16(gelu(z+bias));  1: C += z+bias, Cb = bf16(C);  2: C = z.
template<int EPI, int TM, int TN>
__global__ __launch_bounds__(256) void mgemm(
    const unsigned short* __restrict__ A,
    const unsigned short* __restrict__ Bt,
    const float* __restrict__ bias,
    float* __restrict__ C, unsigned short* __restrict__ Cb,
    int N, int K)
{
  constexpr int PA = TM/64, PB = TN/64;      // 16B chunks per thread
  constexpr int WM = TM/2, WN = TN/2;
  constexpr int AM = WM/16, AN = WN/16;
  constexpr int ASTG = TM*32, BSTG = TN*32;  // shorts per LDS stage
  __shared__ unsigned short As[2*ASTG];
  __shared__ unsigned short Bs[2*BSTG];
  int tid = threadIdx.x;
  int lane = tid & 63, w = tid >> 6;
  int wr = w >> 1, wc = w & 1;
  int m0 = blockIdx.y * TM, n0 = blockIdx.x * TN;

  const unsigned short* ag[PA];
  const unsigned short* bg[PB];
  int aldst[PA], bldst[PB];
  #pragma unroll
  for (int p=0;p<PA;++p) {
    int ci = p*256 + tid;
    int row = ci >> 2, cp = ci & 3;
    int cg = cp ^ ((row & 3) ^ ((row >> 3) & 1));
    ag[p] = A + (size_t)(m0+row)*K + cg*8;
    aldst[p] = (p*256 + w*64)*8;          // wave-uniform LDS base (shorts)
  }
  #pragma unroll
  for (int p=0;p<PB;++p) {
    int ci = p*256 + tid;
    int row = ci >> 2, cp = ci & 3;
    int cg = cp ^ ((row & 3) ^ ((row >> 3) & 1));
    bg[p] = Bt + (size_t)(n0+row)*K + cg*8;
    bldst[p] = (p*256 + w*64)*8;
  }

  int r = lane & 15, quad = lane >> 4;
  int cidx = quad ^ ((r & 3) ^ ((r >> 3) & 1));
  int aoff[AM], boff[AN];
  #pragma unroll
  for (int i=0;i<AM;++i) aoff[i] = (wr*WM + i*16 + r)*32 + cidx*8;
  #pragma unroll
  for (int j=0;j<AN;++j) boff[j] = (wc*WN + j*16 + r)*32 + cidx*8;

  f32x4 acc[AM][AN];
  #pragma unroll
  for (int i=0;i<AM;++i)
    #pragma unroll
    for (int j=0;j<AN;++j)
      acc[i][j] = (f32x4){0.f,0.f,0.f,0.f};

  // prologue: stage 0
  #pragma unroll
  for (int p=0;p<PA;++p) gload_lds16(ag[p], &As[aldst[p]]);
  #pragma unroll
  for (int p=0;p<PB;++p) gload_lds16(bg[p], &Bs[bldst[p]]);

  int nk = K >> 5;
  for (int ki = 0; ki < nk; ++ki) {
    __syncthreads();                      // stage cur complete (vmcnt drain)
    int cur = ki & 1, nxt = cur ^ 1;
    if (ki + 1 < nk) {                    // prefetch overlaps compute below
      int kk = (ki + 1) << 5;
      #pragma unroll
      for (int p=0;p<PA;++p) gload_lds16(ag[p] + kk, &As[nxt*ASTG + aldst[p]]);
      #pragma unroll
      for (int p=0;p<PB;++p) gload_lds16(bg[p] + kk, &Bs[nxt*BSTG + bldst[p]]);
    }
    short8 af[AM], bfr[AN];
    #pragma unroll
    for (int i=0;i<AM;++i) af[i]  = *(const short8*)&As[cur*ASTG + aoff[i]];
    #pragma unroll
    for (int j=0;j<AN;++j) bfr[j] = *(const short8*)&Bs[cur*BSTG + boff[j]];
    #pragma unroll
    for (int i=0;i<AM;++i)
      #pragma unroll
      for (int j=0;j<AN;++j)
        acc[i][j] = __builtin_amdgcn_mfma_f32_16x16x32_bf16(af[i], bfr[j], acc[i][j], 0, 0, 0);
  }

  #pragma unroll
  for (int i=0;i<AM;++i) {
    int rowb = m0 + wr*WM + i*16 + quad*4;
    #pragma unroll
    for (int j=0;j<AN;++j) {
      int col = n0 + wc*WN + j*16 + r;
      float bv = 0.f;
      if (EPI != 2) bv = bias[col];
      #pragma unroll
      for (int reg=0;reg<4;++reg) {
        size_t idx = (size_t)(rowb + reg) * N + col;
        float z = acc[i][j][reg] + bv;
        if (EPI == 0) {
          z = 0.5f * z * (1.0f + erff(z * 0.707106781186547524f));
          Cb[idx] = f2bf(z);
        } else if (EPI == 1) {
          float hv = C[idx] + z;
          C[idx] = hv;
          Cb[idx] = f2bf(hv);
        } else {
          C[idx] = z;
        }
      }
    }
  }
}

extern "C" void kernel_launch(void* const* d_in, const int* in_sizes, int n_in,
                              void* d_out, int out_size, void* d_ws, size_t ws_size,
                              hipStream_t stream) {
  const int*   x     = (const int*)  d_in[0];
  const float* embed = (const float*)d_in[1];
  const float* kvec  = (const float*)d_in[2];
  const float* g     = (const float*)d_in[3];
  const float* bt    = (const float*)d_in[4];
  const float* W1    = (const float*)d_in[5];
  const float* b1    = (const float*)d_in[6];
  const float* W2    = (const float*)d_in[7];
  const float* b2    = (const float*)d_in[8];
  float* out = (float*)d_out;

  const size_t NTD = (size_t)Bc * Tc * Dc;   // 4,194,304
  const size_t NTH = (size_t)Bc * Tc * Hc;   // 16,777,216
  char* wsb = (char*)d_ws;
  float* h      = (float*)wsb;                wsb += NTD*4;               // 16MB
  float* tmpA   = (float*)wsb;                wsb += NTD*4;               // 16MB
  float* part   = (float*)wsb;                wsb += (size_t)Bc*NCF*Dc*4; // 512KB
  unsigned short* yb   = (unsigned short*)wsb; wsb += NTD*2;              // 8MB
  unsigned short* a1b  = (unsigned short*)wsb; wsb += NTH*2;              // 32MB
  unsigned short* hb   = (unsigned short*)wsb; wsb += NTD*2;              // 8MB
  unsigned short* W1t  = (unsigned short*)wsb; wsb += (size_t)3*Dc*Hc*2;  // 6MB
  unsigned short* W2t  = (unsigned short*)wsb; wsb += (size_t)3*Dc*Hc*2;  // 6MB
  unsigned short* emb  = (unsigned short*)wsb; wsb += (size_t)Vc*Dc*2;

  // weight prep (per call)
  transpose_to_bf16<<<dim3(Hc/32, Dc/32, 3), 256, 0, stream>>>(W1, W1t, Dc, Hc);
  transpose_to_bf16<<<dim3(Dc/32, Hc/32, 3), 256, 0, stream>>>(W2, W2t, Hc, Dc);
  conv_bf16<<<dim3(Vc*Dc/256), 256, 0, stream>>>(embed, emb, Vc*Dc);

  // prologue
  embed_boundary<<<dim3(Bc*Tc/4), 256, 0, stream>>>(x, embed, tmpA);
  part_sums<<<dim3(NCF, Bc), 512, 0, stream>>>(tmpA, part);
  bd_apply<<<dim3(NCF, Bc), 512, 0, stream>>>(tmpA, part, x, embed, h);

  for (int l = 0; l < 3; ++l) {
    part_sums<<<dim3(NCF, Bc), 512, 0, stream>>>(h, part);
    mag_scan_ln<<<dim3(NCF, Bc), 512, 0, stream>>>(h, part, kvec, l, g, bt, yb);
    // z = gelu(y @ W1 + b1): M=8192 N=2048 K=512 -> a1b (bf16); 1024 blocks
    mgemm<0,128,128><<<dim3(Hc/128, Bc*Tc/128), 256, 0, stream>>>(
        yb, W1t + (size_t)l*Hc*Dc, b1 + (size_t)l*Hc, nullptr, a1b, Hc, Dc);
    // h += z @ W2 + b2: M=8192 N=512 K=2048; TN=64 -> 512 blocks (2/CU)
    mgemm<1,128,64><<<dim3(Dc/64, Bc*Tc/128), 256, 0, stream>>>(
        a1b, W2t + (size_t)l*Dc*Hc, b2 + (size_t)l*Dc, h, hb, Dc, Hc);
  }
  // out = h @ embed^T: M=8192 N=256 K=512; 64x64 tile -> 512 blocks
  mgemm<2,64,64><<<dim3(Vc/64, Bc*Tc/64), 256, 0, stream>>>(
      hb, emb, nullptr, out, nullptr, Vc, Dc);
}

// Round 5
// 514.914 us; speedup vs baseline: 4.0278x; 1.0832x over previous
//
#include <hip/hip_runtime.h>
#include <math.h>

// DeltaLM: B=4 T=2048 D=512 H=2048 L=3 V=256
// decay einsum == geometric scan S[i]=h[i]+w*S[i-1], w=exp(-softplus(k)),
// w^32~6e-19 -> 32-step warmup chunked scan is exact in fp32.
// Round 5: R4 counters showed mgemm<1> FETCH=140MB vs 50MB ideal (A-tiles
// refetched by all 8 XCDs; x-fastest grid scatters A-sharing blocks).
// (1) XCD-aware 1D grid remap: row = bid % nrow -> A-sharing blocks have
//     equal bid%8 -> same XCD -> A fetched once per XCD.
// (2) mgemm<1> BK=64: 32 barrier drains instead of 64, 16 MFMA/barrier.
// (3) dead hb store skipped for l<2.

constexpr int Bc = 4, Tc = 2048, Dc = 512, Hc = 2048, Vc = 256;
constexpr int TSF = 32, NCF = 64, WARM = 32;   // fine time chunks: 64 x 32

typedef __attribute__((ext_vector_type(8))) short short8;
typedef __attribute__((ext_vector_type(4))) float f32x4;

__device__ inline unsigned short f2bf(float f) {  // RNE fp32->bf16
  unsigned int u = __float_as_uint(f);
  u += 0x7fffu + ((u >> 16) & 1u);
  return (unsigned short)(u >> 16);
}

__device__ inline void gload_lds16(const void* g, void* l) {
  __builtin_amdgcn_global_load_lds(
      (const __attribute__((address_space(1))) void*)g,
      (__attribute__((address_space(3))) void*)l, 16, 0, 0);
}

// ---------- embed gather + cumprod(feature) + tanh ----------
__global__ __launch_bounds__(256) void embed_boundary(
    const int* __restrict__ x, const float* __restrict__ embed,
    float* __restrict__ th)
{
  int token = blockIdx.x * 4 + (threadIdx.x >> 6);
  int lane  = threadIdx.x & 63;
  int row = x[token];
  const float* e = embed + (size_t)row * Dc + lane * 8;
  float v[8];
  {
    float4 a = *(const float4*)e;
    float4 b = *(const float4*)(e + 4);
    v[0]=a.x; v[1]=a.y; v[2]=a.z; v[3]=a.w;
    v[4]=b.x; v[5]=b.y; v[6]=b.z; v[7]=b.w;
  }
  float p = v[0];
  #pragma unroll
  for (int j=1;j<8;++j) p *= v[j];
  float incl = p;
  #pragma unroll
  for (int off=1; off<64; off<<=1) {
    float t = __shfl_up(incl, off);
    if (lane >= off) incl *= t;
  }
  float excl = __shfl_up(incl, 1);
  if (lane == 0) excl = 1.0f;
  float c = excl;
  float o[8];
  #pragma unroll
  for (int j=0;j<8;++j) { c *= v[j]; o[j] = tanhf(c); }
  float* dst = th + (size_t)token * Dc + lane * 8;
  *(float4*)dst     = make_float4(o[0],o[1],o[2],o[3]);
  *(float4*)(dst+4) = make_float4(o[4],o[5],o[6],o[7]);
}

// ---------- chunk partial sums over time ----------
__global__ __launch_bounds__(512) void part_sums(
    const float* __restrict__ src, float* __restrict__ part)
{
  int c = blockIdx.x, b = blockIdx.y, d = threadIdx.x;
  const float* p = src + ((size_t)b * Tc + c * TSF) * Dc + d;
  float s = 0.f;
  #pragma unroll
  for (int t=0;t<TSF;++t) s += p[(size_t)t*Dc];
  part[((size_t)b*NCF + c)*Dc + d] = s;
}

// ---------- bd = cumsum_t(th); h = embed[x]*(1+bd) ----------
__global__ __launch_bounds__(512) void bd_apply(
    const float* __restrict__ th, const float* __restrict__ part,
    const int* __restrict__ x, const float* __restrict__ embed,
    float* __restrict__ h)
{
  int c = blockIdx.x, b = blockIdx.y, d = threadIdx.x;
  float acc = 0.f;
  for (int cc=0; cc<c; ++cc) acc += part[((size_t)b*NCF+cc)*Dc + d];
  #pragma unroll
  for (int t=0;t<TSF;++t) {
    int tt = c*TSF + t;
    size_t idx = ((size_t)b*Tc + tt)*Dc + d;
    acc += th[idx];
    int row = x[b*Tc + tt];
    float e = embed[(size_t)row*Dc + d];
    h[idx] = e * (1.0f + acc);
  }
}

// ---------- fused: mag (LDS only) + geometric scan + LayerNorm -> bf16 ----
__global__ __launch_bounds__(512) void mag_scan_ln(
    const float* __restrict__ h, const float* __restrict__ part,
    const float* __restrict__ kvec, int l,
    const float* __restrict__ g, const float* __restrict__ bt,
    unsigned short* __restrict__ yb)
{
  __shared__ float redA[8][TSF];
  __shared__ float redB[8][TSF];
  __shared__ float mag[TSF], muS[TSF], rsS[TSF];
  int c = blockIdx.x, b = blockIdx.y, d = threadIdx.x;
  int lane = d & 63, wv = d >> 6;
  float acc = 0.f;
  for (int cc=0; cc<c; ++cc) acc += part[((size_t)b*NCF+cc)*Dc + d];
  int t0 = c * TSF;
  const float* hbase = h + (size_t)b*Tc*Dc + d;
  float hp = (t0 > 0) ? hbase[(size_t)(t0-1)*Dc] : 0.f;
  float hv[TSF];
  #pragma unroll
  for (int t=0;t<TSF;++t) {
    hv[t] = hbase[(size_t)(t0+t)*Dc];
    acc += hv[t];
    float diff = acc - hp;
    hp = hv[t];
    float s = diff * diff;
    #pragma unroll
    for (int off=32; off; off>>=1) s += __shfl_down(s, off);
    if (!lane) redA[wv][t] = s;
  }
  float kk = kvec[l];
  float sp = kk > 0.f ? kk + log1pf(expf(-kk)) : log1pf(expf(kk));
  float w = expf(-sp);
  int ts = t0 - WARM; if (ts < 0) ts = 0;
  float s = 0.f;
  for (int t=ts; t<t0; ++t) s = hbase[(size_t)t*Dc] + w*s;
  __syncthreads();
  if (d < TSF) {
    float m = 0.f;
    #pragma unroll
    for (int w2=0;w2<8;++w2) m += redA[w2][d];
    mag[d] = sqrtf(m);
  }
  __syncthreads();
  #pragma unroll
  for (int t=0;t<TSF;++t) {
    s = hv[t] + w * s;
    float cv = mag[t] * fabsf(s);
    hv[t] = cv;
    float s1 = cv, s2 = cv * cv;
    #pragma unroll
    for (int off=32; off; off>>=1) {
      s1 += __shfl_down(s1, off);
      s2 += __shfl_down(s2, off);
    }
    if (!lane) { redA[wv][t] = s1; redB[wv][t] = s2; }
  }
  __syncthreads();
  if (d < TSF) {
    float m1 = 0.f, m2 = 0.f;
    #pragma unroll
    for (int w2=0;w2<8;++w2) { m1 += redA[w2][d]; m2 += redB[w2][d]; }
    float mu = m1 * (1.f/Dc);
    float var = fmaxf(m2 * (1.f/Dc) - mu*mu, 0.f);
    muS[d] = mu;
    rsS[d] = rsqrtf(var + 1e-3f);
  }
  __syncthreads();
  float gv = g[l*Dc + d], bv = bt[l*Dc + d];
  unsigned short* yp = yb + ((size_t)b*Tc + t0)*Dc + d;
  #pragma unroll
  for (int t=0;t<TSF;++t)
    yp[(size_t)t*Dc] = f2bf((hv[t] - muS[t]) * rsS[t] * gv + bv);
}

// ---------- W (L,R,C) fp32 -> Wt (L,C,R) bf16 ----------
__global__ __launch_bounds__(256) void transpose_to_bf16(
    const float* __restrict__ W, unsigned short* __restrict__ Wt, int R, int C)
{
  __shared__ float tile[32][33];
  int l = blockIdx.z;
  const float* Wl = W + (size_t)l * R * C;
  unsigned short* Wtl = Wt + (size_t)l * R * C;
  int c0 = blockIdx.x * 32, r0 = blockIdx.y * 32;
  int tx = threadIdx.x & 31, ty = threadIdx.x >> 5;
  for (int i = ty; i < 32; i += 8)
    tile[i][tx] = Wl[(size_t)(r0+i)*C + (c0+tx)];
  __syncthreads();
  for (int i = ty; i < 32; i += 8)
    Wtl[(size_t)(c0+i)*R + (r0+tx)] = f2bf(tile[tx][i]);
}

__global__ __launch_bounds__(256) void conv_bf16(
    const float* __restrict__ src, unsigned short* __restrict__ dst, int n)
{
  int i = blockIdx.x * 256 + threadIdx.x;
  if (i < n) dst[i] = f2bf(src[i]);
}

// ---------- bf16 MFMA GEMM, dbuf LDS, 1 barrier/K-step, XCD-aware grid ----
// A: MxK bf16 row-major. Bt: NxK bf16 row-major. C = A @ Bt^T.
// 1D grid: row = bid % nrow, col = bid / nrow  ->  A-sharing blocks have
// equal bid%8 -> same XCD -> A-tile fetched once per XCD (R4: FETCH 2.8x).
// LDS 16B-chunk XOR swizzle keeps both staging and ds_read_b128 conflict-lite.
// EPI 0: Cb=bf16(gelu(z+bias)); 1: C+=z+bias, Cb=bf16(C) if Cb; 2: C=z.
template<int CH> __device__ inline int swz(int row) {
  if constexpr (CH == 8) return row & 7;
  else return (row & 3) ^ ((row >> 3) & 1);
}

template<int EPI, int TM, int TN, int BK>
__global__ __launch_bounds__(256) void mgemm(
    const unsigned short* __restrict__ A,
    const unsigned short* __restrict__ Bt,
    const float* __restrict__ bias,
    float* __restrict__ C, unsigned short* __restrict__ Cb,
    int N, int K, int nrow)
{
  constexpr int CH = BK / 8;                   // 16B chunks per tile row
  constexpr int PA = TM*CH/256, PB = TN*CH/256;
  constexpr int WM = TM/2, WN = TN/2;
  constexpr int AM = WM/16, AN = WN/16;
  constexpr int NKH = BK/32;
  constexpr int ASTG = TM*BK, BSTG = TN*BK;    // shorts per LDS stage
  __shared__ unsigned short As[2*ASTG];
  __shared__ unsigned short Bs[2*BSTG];
  int tid = threadIdx.x;
  int lane = tid & 63, w = tid >> 6;
  int wr = w >> 1, wc = w & 1;
  int bid = blockIdx.x;
  int m0 = (bid % nrow) * TM, n0 = (bid / nrow) * TN;

  const unsigned short* ag[PA];
  const unsigned short* bg[PB];
  int aldst[PA], bldst[PB];
  #pragma unroll
  for (int p=0;p<PA;++p) {
    int ci = p*256 + tid;
    int row = ci / CH, cp = ci % CH;
    int cg = cp ^ swz<CH>(row);
    ag[p] = A + (size_t)(m0+row)*K + cg*8;
    aldst[p] = (p*256 + w*64)*8;               // wave-uniform LDS base
  }
  #pragma unroll
  for (int p=0;p<PB;++p) {
    int ci = p*256 + tid;
    int row = ci / CH, cp = ci % CH;
    int cg = cp ^ swz<CH>(row);
    bg[p] = Bt + (size_t)(n0+row)*K + cg*8;
    bldst[p] = (p*256 + w*64)*8;
  }

  int r = lane & 15, quad = lane >> 4;
  int aoff[NKH][AM], boff[NKH][AN];
  #pragma unroll
  for (int kh=0;kh<NKH;++kh) {
    int cb = kh*4 + quad;
    #pragma unroll
    for (int i=0;i<AM;++i)
      aoff[kh][i] = (wr*WM + i*16 + r)*BK + (cb ^ swz<CH>(r))*8;
    #pragma unroll
    for (int j=0;j<AN;++j)
      boff[kh][j] = (wc*WN + j*16 + r)*BK + (cb ^ swz<CH>(r))*8;
  }

  f32x4 acc[AM][AN];
  #pragma unroll
  for (int i=0;i<AM;++i)
    #pragma unroll
    for (int j=0;j<AN;++j)
      acc[i][j] = (f32x4){0.f,0.f,0.f,0.f};

  // prologue: stage 0
  #pragma unroll
  for (int p=0;p<PA;++p) gload_lds16(ag[p], &As[aldst[p]]);
  #pragma unroll
  for (int p=0;p<PB;++p) gload_lds16(bg[p], &Bs[bldst[p]]);

  int nk = K / BK;
  for (int ki = 0; ki < nk; ++ki) {
    __syncthreads();                           // stage cur complete
    int cur = ki & 1, nxt = cur ^ 1;
    if (ki + 1 < nk) {                         // prefetch overlaps compute
      int kk = (ki + 1) * BK;
      #pragma unroll
      for (int p=0;p<PA;++p) gload_lds16(ag[p] + kk, &As[nxt*ASTG + aldst[p]]);
      #pragma unroll
      for (int p=0;p<PB;++p) gload_lds16(bg[p] + kk, &Bs[nxt*BSTG + bldst[p]]);
    }
    #pragma unroll
    for (int kh=0;kh<NKH;++kh) {
      short8 af[AM], bfr[AN];
      #pragma unroll
      for (int i=0;i<AM;++i) af[i]  = *(const short8*)&As[cur*ASTG + aoff[kh][i]];
      #pragma unroll
      for (int j=0;j<AN;++j) bfr[j] = *(const short8*)&Bs[cur*BSTG + boff[kh][j]];
      #pragma unroll
      for (int i=0;i<AM;++i)
        #pragma unroll
        for (int j=0;j<AN;++j)
          acc[i][j] = __builtin_amdgcn_mfma_f32_16x16x32_bf16(af[i], bfr[j], acc[i][j], 0, 0, 0);
    }
  }

  #pragma unroll
  for (int i=0;i<AM;++i) {
    int rowb = m0 + wr*WM + i*16 + quad*4;
    #pragma unroll
    for (int j=0;j<AN;++j) {
      int col = n0 + wc*WN + j*16 + r;
      float bv = 0.f;
      if (EPI != 2) bv = bias[col];
      #pragma unroll
      for (int reg=0;reg<4;++reg) {
        size_t idx = (size_t)(rowb + reg) * N + col;
        float z = acc[i][j][reg] + bv;
        if (EPI == 0) {
          z = 0.5f * z * (1.0f + erff(z * 0.707106781186547524f));
          Cb[idx] = f2bf(z);
        } else if (EPI == 1) {
          float hv = C[idx] + z;
          C[idx] = hv;
          if (Cb) Cb[idx] = f2bf(hv);
        } else {
          C[idx] = z;
        }
      }
    }
  }
}

extern "C" void kernel_launch(void* const* d_in, const int* in_sizes, int n_in,
                              void* d_out, int out_size, void* d_ws, size_t ws_size,
                              hipStream_t stream) {
  const int*   x     = (const int*)  d_in[0];
  const float* embed = (const float*)d_in[1];
  const float* kvec  = (const float*)d_in[2];
  const float* g     = (const float*)d_in[3];
  const float* bt    = (const float*)d_in[4];
  const float* W1    = (const float*)d_in[5];
  const float* b1    = (const float*)d_in[6];
  const float* W2    = (const float*)d_in[7];
  const float* b2    = (const float*)d_in[8];
  float* out = (float*)d_out;

  const size_t NTD = (size_t)Bc * Tc * Dc;   // 4,194,304
  const size_t NTH = (size_t)Bc * Tc * Hc;   // 16,777,216
  char* wsb = (char*)d_ws;
  float* h      = (float*)wsb;                wsb += NTD*4;               // 16MB
  float* tmpA   = (float*)wsb;                wsb += NTD*4;               // 16MB
  float* part   = (float*)wsb;                wsb += (size_t)Bc*NCF*Dc*4; // 512KB
  unsigned short* yb   = (unsigned short*)wsb; wsb += NTD*2;              // 8MB
  unsigned short* a1b  = (unsigned short*)wsb; wsb += NTH*2;              // 32MB
  unsigned short* hb   = (unsigned short*)wsb; wsb += NTD*2;              // 8MB
  unsigned short* W1t  = (unsigned short*)wsb; wsb += (size_t)3*Dc*Hc*2;  // 6MB
  unsigned short* W2t  = (unsigned short*)wsb; wsb += (size_t)3*Dc*Hc*2;  // 6MB
  unsigned short* emb  = (unsigned short*)wsb; wsb += (size_t)Vc*Dc*2;

  // weight prep (per call)
  transpose_to_bf16<<<dim3(Hc/32, Dc/32, 3), 256, 0, stream>>>(W1, W1t, Dc, Hc);
  transpose_to_bf16<<<dim3(Dc/32, Hc/32, 3), 256, 0, stream>>>(W2, W2t, Hc, Dc);
  conv_bf16<<<dim3(Vc*Dc/256), 256, 0, stream>>>(embed, emb, Vc*Dc);

  // prologue
  embed_boundary<<<dim3(Bc*Tc/4), 256, 0, stream>>>(x, embed, tmpA);
  part_sums<<<dim3(NCF, Bc), 512, 0, stream>>>(tmpA, part);
  bd_apply<<<dim3(NCF, Bc), 512, 0, stream>>>(tmpA, part, x, embed, h);

  for (int l = 0; l < 3; ++l) {
    part_sums<<<dim3(NCF, Bc), 512, 0, stream>>>(h, part);
    mag_scan_ln<<<dim3(NCF, Bc), 512, 0, stream>>>(h, part, kvec, l, g, bt, yb);
    // z = gelu(y @ W1 + b1): M=8192 N=2048 K=512; 1024 blocks, nrow=64
    mgemm<0,128,128,32><<<dim3(64*(Hc/128)), 256, 0, stream>>>(
        yb, W1t + (size_t)l*Hc*Dc, b1 + (size_t)l*Hc, nullptr, a1b, Hc, Dc, 64);
    // h += z @ W2 + b2: M=8192 N=512 K=2048; BK=64; 512 blocks, nrow=64
    mgemm<1,128,64,64><<<dim3(64*(Dc/64)), 256, 0, stream>>>(
        a1b, W2t + (size_t)l*Dc*Hc, b2 + (size_t)l*Dc, h,
        (l == 2) ? hb : nullptr, Dc, Hc, 64);
  }
  // out = h @ embed^T: M=8192 N=256 K=512; 64x64 tiles, nrow=128
  mgemm<2,64,64,32><<<dim3(128*(Vc/64)), 256, 0, stream>>>(
      hb, emb, nullptr, out, nullptr, Vc, Dc, 128);
}

// Round 6
// 453.563 us; speedup vs baseline: 4.5726x; 1.1353x over previous
//
#include <hip/hip_runtime.h>
#include <math.h>

// DeltaLM: B=4 T=2048 D=512 H=2048 L=3 V=256
// decay einsum == geometric scan S[i]=h[i]+w*S[i-1], w=exp(-softplus(k)),
// w^32~6e-19 -> 32-step warmup chunked scan is exact in fp32.
// Round 6: R5 showed mag_scan_ln latency-bound (17% occ, 8% VALU): O(c)
// prefix loops + 256 blocks. Now: TSF=16/NCF=128 (512 blocks, 2/CU),
// exclusive-prefix precomputed in-place (part_prefix), h chunk-partials
// produced for free by bd_apply + mgemm<1> epilogue butterfly (part_sums
// survives only for th).

constexpr int Bc = 4, Tc = 2048, Dc = 512, Hc = 2048, Vc = 256;
constexpr int TSF = 16, NCF = 128, WARM = 32;  // fine time chunks: 128 x 16

typedef __attribute__((ext_vector_type(8))) short short8;
typedef __attribute__((ext_vector_type(4))) float f32x4;

__device__ inline unsigned short f2bf(float f) {  // RNE fp32->bf16
  unsigned int u = __float_as_uint(f);
  u += 0x7fffu + ((u >> 16) & 1u);
  return (unsigned short)(u >> 16);
}

__device__ inline void gload_lds16(const void* g, void* l) {
  __builtin_amdgcn_global_load_lds(
      (const __attribute__((address_space(1))) void*)g,
      (__attribute__((address_space(3))) void*)l, 16, 0, 0);
}

// ---------- embed gather + cumprod(feature) + tanh ----------
__global__ __launch_bounds__(256) void embed_boundary(
    const int* __restrict__ x, const float* __restrict__ embed,
    float* __restrict__ th)
{
  int token = blockIdx.x * 4 + (threadIdx.x >> 6);
  int lane  = threadIdx.x & 63;
  int row = x[token];
  const float* e = embed + (size_t)row * Dc + lane * 8;
  float v[8];
  {
    float4 a = *(const float4*)e;
    float4 b = *(const float4*)(e + 4);
    v[0]=a.x; v[1]=a.y; v[2]=a.z; v[3]=a.w;
    v[4]=b.x; v[5]=b.y; v[6]=b.z; v[7]=b.w;
  }
  float p = v[0];
  #pragma unroll
  for (int j=1;j<8;++j) p *= v[j];
  float incl = p;
  #pragma unroll
  for (int off=1; off<64; off<<=1) {
    float t = __shfl_up(incl, off);
    if (lane >= off) incl *= t;
  }
  float excl = __shfl_up(incl, 1);
  if (lane == 0) excl = 1.0f;
  float c = excl;
  float o[8];
  #pragma unroll
  for (int j=0;j<8;++j) { c *= v[j]; o[j] = tanhf(c); }
  float* dst = th + (size_t)token * Dc + lane * 8;
  *(float4*)dst     = make_float4(o[0],o[1],o[2],o[3]);
  *(float4*)(dst+4) = make_float4(o[4],o[5],o[6],o[7]);
}

// ---------- chunk partial sums over time (th only) ----------
__global__ __launch_bounds__(512) void part_sums(
    const float* __restrict__ src, float* __restrict__ part)
{
  int c = blockIdx.x, b = blockIdx.y, d = threadIdx.x;
  const float* p = src + ((size_t)b * Tc + c * TSF) * Dc + d;
  float s = 0.f;
  #pragma unroll
  for (int t=0;t<TSF;++t) s += p[(size_t)t*Dc];
  part[((size_t)b*NCF + c)*Dc + d] = s;
}

// ---------- in-place exclusive prefix over chunks, per (b,d) ----------
__global__ __launch_bounds__(256) void part_prefix(float* __restrict__ part)
{
  int gid = blockIdx.x * 256 + threadIdx.x;   // 2048 threads
  int b = gid >> 9, d = gid & 511;
  float run = 0.f;
  for (int c = 0; c < NCF; ++c) {
    size_t idx = ((size_t)b*NCF + c)*Dc + d;
    float v = part[idx];
    part[idx] = run;
    run += v;
  }
}

// ---------- bd = cumsum_t(th); h = embed[x]*(1+bd); writes h chunk sum ----
__global__ __launch_bounds__(512) void bd_apply(
    const float* __restrict__ th, const float* __restrict__ partA,
    const int* __restrict__ x, const float* __restrict__ embed,
    float* __restrict__ h, float* __restrict__ partB)
{
  int c = blockIdx.x, b = blockIdx.y, d = threadIdx.x;
  float acc = partA[((size_t)b*NCF + c)*Dc + d];   // exclusive prefix (th)
  float hsum = 0.f;
  #pragma unroll
  for (int t=0;t<TSF;++t) {
    int tt = c*TSF + t;
    size_t idx = ((size_t)b*Tc + tt)*Dc + d;
    acc += th[idx];
    int row = x[b*Tc + tt];
    float e = embed[(size_t)row*Dc + d];
    float hv = e * (1.0f + acc);
    h[idx] = hv;
    hsum += hv;
  }
  partB[((size_t)b*NCF + c)*Dc + d] = hsum;        // raw chunk sum (h)
}

// ---------- fused: mag (LDS only) + geometric scan + LayerNorm -> bf16 ----
__global__ __launch_bounds__(512) void mag_scan_ln(
    const float* __restrict__ h, const float* __restrict__ part,
    const float* __restrict__ kvec, int l,
    const float* __restrict__ g, const float* __restrict__ bt,
    unsigned short* __restrict__ yb)
{
  __shared__ float redA[8][TSF];
  __shared__ float redB[8][TSF];
  __shared__ float mag[TSF], muS[TSF], rsS[TSF];
  int c = blockIdx.x, b = blockIdx.y, d = threadIdx.x;
  int lane = d & 63, wv = d >> 6;
  float acc = part[((size_t)b*NCF + c)*Dc + d];    // exclusive prefix (h)
  int t0 = c * TSF;
  const float* hbase = h + (size_t)b*Tc*Dc + d;
  float hp = (t0 > 0) ? hbase[(size_t)(t0-1)*Dc] : 0.f;
  float hv[TSF];
  #pragma unroll
  for (int t=0;t<TSF;++t) {
    hv[t] = hbase[(size_t)(t0+t)*Dc];
    acc += hv[t];
    float diff = acc - hp;
    hp = hv[t];
    float s = diff * diff;
    #pragma unroll
    for (int off=32; off; off>>=1) s += __shfl_down(s, off);
    if (!lane) redA[wv][t] = s;
  }
  float kk = kvec[l];
  float sp = kk > 0.f ? kk + log1pf(expf(-kk)) : log1pf(expf(kk));
  float w = expf(-sp);
  int ts = t0 - WARM; if (ts < 0) ts = 0;
  float s = 0.f;
  for (int t=ts; t<t0; ++t) s = hbase[(size_t)t*Dc] + w*s;
  __syncthreads();
  if (d < TSF) {
    float m = 0.f;
    #pragma unroll
    for (int w2=0;w2<8;++w2) m += redA[w2][d];
    mag[d] = sqrtf(m);
  }
  __syncthreads();
  #pragma unroll
  for (int t=0;t<TSF;++t) {
    s = hv[t] + w * s;
    float cv = mag[t] * fabsf(s);
    hv[t] = cv;
    float s1 = cv, s2 = cv * cv;
    #pragma unroll
    for (int off=32; off; off>>=1) {
      s1 += __shfl_down(s1, off);
      s2 += __shfl_down(s2, off);
    }
    if (!lane) { redA[wv][t] = s1; redB[wv][t] = s2; }
  }
  __syncthreads();
  if (d < TSF) {
    float m1 = 0.f, m2 = 0.f;
    #pragma unroll
    for (int w2=0;w2<8;++w2) { m1 += redA[w2][d]; m2 += redB[w2][d]; }
    float mu = m1 * (1.f/Dc);
    float var = fmaxf(m2 * (1.f/Dc) - mu*mu, 0.f);
    muS[d] = mu;
    rsS[d] = rsqrtf(var + 1e-3f);
  }
  __syncthreads();
  float gv = g[l*Dc + d], bv = bt[l*Dc + d];
  unsigned short* yp = yb + ((size_t)b*Tc + t0)*Dc + d;
  #pragma unroll
  for (int t=0;t<TSF;++t)
    yp[(size_t)t*Dc] = f2bf((hv[t] - muS[t]) * rsS[t] * gv + bv);
}

// ---------- W (L,R,C) fp32 -> Wt (L,C,R) bf16 ----------
__global__ __launch_bounds__(256) void transpose_to_bf16(
    const float* __restrict__ W, unsigned short* __restrict__ Wt, int R, int C)
{
  __shared__ float tile[32][33];
  int l = blockIdx.z;
  const float* Wl = W + (size_t)l * R * C;
  unsigned short* Wtl = Wt + (size_t)l * R * C;
  int c0 = blockIdx.x * 32, r0 = blockIdx.y * 32;
  int tx = threadIdx.x & 31, ty = threadIdx.x >> 5;
  for (int i = ty; i < 32; i += 8)
    tile[i][tx] = Wl[(size_t)(r0+i)*C + (c0+tx)];
  __syncthreads();
  for (int i = ty; i < 32; i += 8)
    Wtl[(size_t)(c0+i)*R + (r0+tx)] = f2bf(tile[tx][i]);
}

__global__ __launch_bounds__(256) void conv_bf16(
    const float* __restrict__ src, unsigned short* __restrict__ dst, int n)
{
  int i = blockIdx.x * 256 + threadIdx.x;
  if (i < n) dst[i] = f2bf(src[i]);
}

// ---------- bf16 MFMA GEMM, dbuf LDS, 1 barrier/K-step, XCD-aware grid ----
// A: MxK bf16 row-major. Bt: NxK bf16 row-major. C = A @ Bt^T.
// 1D grid: row = bid % nrow -> A-sharing blocks pinned to one XCD.
// EPI 0: Cb=bf16(gelu(z+bias)); 1: C+=z+bias (+ chunk partials via butterfly,
// + optional Cb=bf16); 2: C=z.
template<int CH> __device__ inline int swz(int row) {
  if constexpr (CH == 8) return row & 7;
  else return (row & 3) ^ ((row >> 3) & 1);
}

template<int EPI, int TM, int TN, int BK>
__global__ __launch_bounds__(256) void mgemm(
    const unsigned short* __restrict__ A,
    const unsigned short* __restrict__ Bt,
    const float* __restrict__ bias,
    float* __restrict__ C, unsigned short* __restrict__ Cb,
    float* __restrict__ part,
    int N, int K, int nrow)
{
  constexpr int CH = BK / 8;                   // 16B chunks per tile row
  constexpr int PA = TM*CH/256, PB = TN*CH/256;
  constexpr int WM = TM/2, WN = TN/2;
  constexpr int AM = WM/16, AN = WN/16;
  constexpr int NKH = BK/32;
  constexpr int ASTG = TM*BK, BSTG = TN*BK;    // shorts per LDS stage
  __shared__ unsigned short As[2*ASTG];
  __shared__ unsigned short Bs[2*BSTG];
  int tid = threadIdx.x;
  int lane = tid & 63, w = tid >> 6;
  int wr = w >> 1, wc = w & 1;
  int bid = blockIdx.x;
  int m0 = (bid % nrow) * TM, n0 = (bid / nrow) * TN;

  const unsigned short* ag[PA];
  const unsigned short* bg[PB];
  int aldst[PA], bldst[PB];
  #pragma unroll
  for (int p=0;p<PA;++p) {
    int ci = p*256 + tid;
    int row = ci / CH, cp = ci % CH;
    int cg = cp ^ swz<CH>(row);
    ag[p] = A + (size_t)(m0+row)*K + cg*8;
    aldst[p] = (p*256 + w*64)*8;               // wave-uniform LDS base
  }
  #pragma unroll
  for (int p=0;p<PB;++p) {
    int ci = p*256 + tid;
    int row = ci / CH, cp = ci % CH;
    int cg = cp ^ swz<CH>(row);
    bg[p] = Bt + (size_t)(n0+row)*K + cg*8;
    bldst[p] = (p*256 + w*64)*8;
  }

  int r = lane & 15, quad = lane >> 4;
  int aoff[NKH][AM], boff[NKH][AN];
  #pragma unroll
  for (int kh=0;kh<NKH;++kh) {
    int cb = kh*4 + quad;
    #pragma unroll
    for (int i=0;i<AM;++i)
      aoff[kh][i] = (wr*WM + i*16 + r)*BK + (cb ^ swz<CH>(r))*8;
    #pragma unroll
    for (int j=0;j<AN;++j)
      boff[kh][j] = (wc*WN + j*16 + r)*BK + (cb ^ swz<CH>(r))*8;
  }

  f32x4 acc[AM][AN];
  #pragma unroll
  for (int i=0;i<AM;++i)
    #pragma unroll
    for (int j=0;j<AN;++j)
      acc[i][j] = (f32x4){0.f,0.f,0.f,0.f};

  // prologue: stage 0
  #pragma unroll
  for (int p=0;p<PA;++p) gload_lds16(ag[p], &As[aldst[p]]);
  #pragma unroll
  for (int p=0;p<PB;++p) gload_lds16(bg[p], &Bs[bldst[p]]);

  int nk = K / BK;
  for (int ki = 0; ki < nk; ++ki) {
    __syncthreads();                           // stage cur complete
    int cur = ki & 1, nxt = cur ^ 1;
    if (ki + 1 < nk) {                         // prefetch overlaps compute
      int kk = (ki + 1) * BK;
      #pragma unroll
      for (int p=0;p<PA;++p) gload_lds16(ag[p] + kk, &As[nxt*ASTG + aldst[p]]);
      #pragma unroll
      for (int p=0;p<PB;++p) gload_lds16(bg[p] + kk, &Bs[nxt*BSTG + bldst[p]]);
    }
    #pragma unroll
    for (int kh=0;kh<NKH;++kh) {
      short8 af[AM], bfr[AN];
      #pragma unroll
      for (int i=0;i<AM;++i) af[i]  = *(const short8*)&As[cur*ASTG + aoff[kh][i]];
      #pragma unroll
      for (int j=0;j<AN;++j) bfr[j] = *(const short8*)&Bs[cur*BSTG + boff[kh][j]];
      #pragma unroll
      for (int i=0;i<AM;++i)
        #pragma unroll
        for (int j=0;j<AN;++j)
          acc[i][j] = __builtin_amdgcn_mfma_f32_16x16x32_bf16(af[i], bfr[j], acc[i][j], 0, 0, 0);
    }
  }

  #pragma unroll
  for (int i=0;i<AM;++i) {
    int rowb = m0 + wr*WM + i*16 + quad*4;
    #pragma unroll
    for (int j=0;j<AN;++j) {
      int col = n0 + wc*WN + j*16 + r;
      float bv = 0.f;
      if (EPI != 2) bv = bias[col];
      float ps = 0.f;
      #pragma unroll
      for (int reg=0;reg<4;++reg) {
        size_t idx = (size_t)(rowb + reg) * N + col;
        float z = acc[i][j][reg] + bv;
        if (EPI == 0) {
          z = 0.5f * z * (1.0f + erff(z * 0.707106781186547524f));
          Cb[idx] = f2bf(z);
        } else if (EPI == 1) {
          float hv = C[idx] + z;
          C[idx] = hv;
          ps += hv;
          if (Cb) Cb[idx] = f2bf(hv);
        } else {
          C[idx] = z;
        }
      }
      if (EPI == 1 && part) {
        // chunk (16 rows) sum: butterfly over quad bits (lanes ^16, ^32)
        ps += __shfl_xor(ps, 16);
        ps += __shfl_xor(ps, 32);
        if (quad == 0) {
          int chunk = (m0 + wr*WM + i*16) >> 4;   // TSF=16
          part[(size_t)chunk * N + col] = ps;
        }
      }
    }
  }
}

extern "C" void kernel_launch(void* const* d_in, const int* in_sizes, int n_in,
                              void* d_out, int out_size, void* d_ws, size_t ws_size,
                              hipStream_t stream) {
  const int*   x     = (const int*)  d_in[0];
  const float* embed = (const float*)d_in[1];
  const float* kvec  = (const float*)d_in[2];
  const float* g     = (const float*)d_in[3];
  const float* bt    = (const float*)d_in[4];
  const float* W1    = (const float*)d_in[5];
  const float* b1    = (const float*)d_in[6];
  const float* W2    = (const float*)d_in[7];
  const float* b2    = (const float*)d_in[8];
  float* out = (float*)d_out;

  const size_t NTD = (size_t)Bc * Tc * Dc;   // 4,194,304
  const size_t NTH = (size_t)Bc * Tc * Hc;   // 16,777,216
  char* wsb = (char*)d_ws;
  float* h      = (float*)wsb;                wsb += NTD*4;               // 16MB
  float* tmpA   = (float*)wsb;                wsb += NTD*4;               // 16MB
  float* partA  = (float*)wsb;                wsb += (size_t)Bc*NCF*Dc*4; // 1MB
  float* partB  = (float*)wsb;                wsb += (size_t)Bc*NCF*Dc*4; // 1MB
  unsigned short* yb   = (unsigned short*)wsb; wsb += NTD*2;              // 8MB
  unsigned short* a1b  = (unsigned short*)wsb; wsb += NTH*2;              // 32MB
  unsigned short* hb   = (unsigned short*)wsb; wsb += NTD*2;              // 8MB
  unsigned short* W1t  = (unsigned short*)wsb; wsb += (size_t)3*Dc*Hc*2;  // 6MB
  unsigned short* W2t  = (unsigned short*)wsb; wsb += (size_t)3*Dc*Hc*2;  // 6MB
  unsigned short* emb  = (unsigned short*)wsb; wsb += (size_t)Vc*Dc*2;

  // weight prep (per call)
  transpose_to_bf16<<<dim3(Hc/32, Dc/32, 3), 256, 0, stream>>>(W1, W1t, Dc, Hc);
  transpose_to_bf16<<<dim3(Dc/32, Hc/32, 3), 256, 0, stream>>>(W2, W2t, Hc, Dc);
  conv_bf16<<<dim3(Vc*Dc/256), 256, 0, stream>>>(embed, emb, Vc*Dc);

  // prologue
  embed_boundary<<<dim3(Bc*Tc/4), 256, 0, stream>>>(x, embed, tmpA);
  part_sums<<<dim3(NCF, Bc), 512, 0, stream>>>(tmpA, partA);
  part_prefix<<<dim3(8), 256, 0, stream>>>(partA);
  bd_apply<<<dim3(NCF, Bc), 512, 0, stream>>>(tmpA, partA, x, embed, h, partB);
  part_prefix<<<dim3(8), 256, 0, stream>>>(partB);

  for (int l = 0; l < 3; ++l) {
    mag_scan_ln<<<dim3(NCF, Bc), 512, 0, stream>>>(h, partB, kvec, l, g, bt, yb);
    // z = gelu(y @ W1 + b1): M=8192 N=2048 K=512; 1024 blocks, nrow=64
    mgemm<0,128,128,32><<<dim3(64*(Hc/128)), 256, 0, stream>>>(
        yb, W1t + (size_t)l*Hc*Dc, b1 + (size_t)l*Hc, nullptr, a1b, nullptr,
        Hc, Dc, 64);
    // h += z @ W2 + b2 (+ h chunk partials): M=8192 N=512 K=2048, BK=64
    mgemm<1,128,64,64><<<dim3(64*(Dc/64)), 256, 0, stream>>>(
        a1b, W2t + (size_t)l*Dc*Hc, b2 + (size_t)l*Dc, h,
        (l == 2) ? hb : nullptr, (l < 2) ? partB : nullptr, Dc, Hc, 64);
    if (l < 2) part_prefix<<<dim3(8), 256, 0, stream>>>(partB);
  }
  // out = h @ embed^T: M=8192 N=256 K=512; 64x64 tiles, nrow=128
  mgemm<2,64,64,32><<<dim3(128*(Vc/64)), 256, 0, stream>>>(
      hb, emb, nullptr, out, nullptr, nullptr, Vc, Dc, 128);
}

// Round 7
// 424.189 us; speedup vs baseline: 4.8893x; 1.0692x over previous
//
#include <hip/hip_runtime.h>
#include <math.h>

// DeltaLM: B=4 T=2048 D=512 H=2048 L=3 V=256
// decay einsum == geometric scan S[i]=h[i]+w*S[i-1], w=exp(-softplus(k)),
// w^32~6e-19 -> 32-step warmup chunked scan is exact in fp32.
// Round 7: R6 showed mgemm<0> latency-bound (MfmaUtil 13%, occ 19%): 128x128
// tile = only 4 blocks/CU on a 16-iter K-loop. Re-tile: mgemm<0> 64x128
// (2048 blocks, ~6/CU), mgemm<1> 64x64 BK=64 (1024 blocks). part_prefix ->
// wave-parallel shuffle scan.

constexpr int Bc = 4, Tc = 2048, Dc = 512, Hc = 2048, Vc = 256;
constexpr int TSF = 16, NCF = 128, WARM = 32;  // fine time chunks: 128 x 16

typedef __attribute__((ext_vector_type(8))) short short8;
typedef __attribute__((ext_vector_type(4))) float f32x4;

__device__ inline unsigned short f2bf(float f) {  // RNE fp32->bf16
  unsigned int u = __float_as_uint(f);
  u += 0x7fffu + ((u >> 16) & 1u);
  return (unsigned short)(u >> 16);
}

__device__ inline void gload_lds16(const void* g, void* l) {
  __builtin_amdgcn_global_load_lds(
      (const __attribute__((address_space(1))) void*)g,
      (__attribute__((address_space(3))) void*)l, 16, 0, 0);
}

// ---------- embed gather + cumprod(feature) + tanh ----------
__global__ __launch_bounds__(256) void embed_boundary(
    const int* __restrict__ x, const float* __restrict__ embed,
    float* __restrict__ th)
{
  int token = blockIdx.x * 4 + (threadIdx.x >> 6);
  int lane  = threadIdx.x & 63;
  int row = x[token];
  const float* e = embed + (size_t)row * Dc + lane * 8;
  float v[8];
  {
    float4 a = *(const float4*)e;
    float4 b = *(const float4*)(e + 4);
    v[0]=a.x; v[1]=a.y; v[2]=a.z; v[3]=a.w;
    v[4]=b.x; v[5]=b.y; v[6]=b.z; v[7]=b.w;
  }
  float p = v[0];
  #pragma unroll
  for (int j=1;j<8;++j) p *= v[j];
  float incl = p;
  #pragma unroll
  for (int off=1; off<64; off<<=1) {
    float t = __shfl_up(incl, off);
    if (lane >= off) incl *= t;
  }
  float excl = __shfl_up(incl, 1);
  if (lane == 0) excl = 1.0f;
  float c = excl;
  float o[8];
  #pragma unroll
  for (int j=0;j<8;++j) { c *= v[j]; o[j] = tanhf(c); }
  float* dst = th + (size_t)token * Dc + lane * 8;
  *(float4*)dst     = make_float4(o[0],o[1],o[2],o[3]);
  *(float4*)(dst+4) = make_float4(o[4],o[5],o[6],o[7]);
}

// ---------- chunk partial sums over time (th only) ----------
__global__ __launch_bounds__(512) void part_sums(
    const float* __restrict__ src, float* __restrict__ part)
{
  int c = blockIdx.x, b = blockIdx.y, d = threadIdx.x;
  const float* p = src + ((size_t)b * Tc + c * TSF) * Dc + d;
  float s = 0.f;
  #pragma unroll
  for (int t=0;t<TSF;++t) s += p[(size_t)t*Dc];
  part[((size_t)b*NCF + c)*Dc + d] = s;
}

// ---------- in-place exclusive prefix over 128 chunks: 1 wave per (b,d) ---
__global__ __launch_bounds__(512) void part_prefix(float* __restrict__ part)
{
  int pair = blockIdx.x * 8 + (threadIdx.x >> 6);   // 2048 (b,d) pairs
  int lane = threadIdx.x & 63;
  int b = pair >> 9, d = pair & 511;
  size_t i0 = ((size_t)b*NCF + 2*lane)*Dc + d;
  float v0 = part[i0];
  float v1 = part[i0 + Dc];
  float ps = v0 + v1;
  float incl = ps;
  #pragma unroll
  for (int off=1; off<64; off<<=1) {
    float t = __shfl_up(incl, off);
    if (lane >= off) incl += t;
  }
  float excl = incl - ps;
  part[i0]      = excl;
  part[i0 + Dc] = excl + v0;
}

// ---------- bd = cumsum_t(th); h = embed[x]*(1+bd); writes h chunk sum ----
__global__ __launch_bounds__(512) void bd_apply(
    const float* __restrict__ th, const float* __restrict__ partA,
    const int* __restrict__ x, const float* __restrict__ embed,
    float* __restrict__ h, float* __restrict__ partB)
{
  int c = blockIdx.x, b = blockIdx.y, d = threadIdx.x;
  float acc = partA[((size_t)b*NCF + c)*Dc + d];   // exclusive prefix (th)
  float hsum = 0.f;
  #pragma unroll
  for (int t=0;t<TSF;++t) {
    int tt = c*TSF + t;
    size_t idx = ((size_t)b*Tc + tt)*Dc + d;
    acc += th[idx];
    int row = x[b*Tc + tt];
    float e = embed[(size_t)row*Dc + d];
    float hv = e * (1.0f + acc);
    h[idx] = hv;
    hsum += hv;
  }
  partB[((size_t)b*NCF + c)*Dc + d] = hsum;        // raw chunk sum (h)
}

// ---------- fused: mag (LDS only) + geometric scan + LayerNorm -> bf16 ----
__global__ __launch_bounds__(512) void mag_scan_ln(
    const float* __restrict__ h, const float* __restrict__ part,
    const float* __restrict__ kvec, int l,
    const float* __restrict__ g, const float* __restrict__ bt,
    unsigned short* __restrict__ yb)
{
  __shared__ float redA[8][TSF];
  __shared__ float redB[8][TSF];
  __shared__ float mag[TSF], muS[TSF], rsS[TSF];
  int c = blockIdx.x, b = blockIdx.y, d = threadIdx.x;
  int lane = d & 63, wv = d >> 6;
  float acc = part[((size_t)b*NCF + c)*Dc + d];    // exclusive prefix (h)
  int t0 = c * TSF;
  const float* hbase = h + (size_t)b*Tc*Dc + d;
  float hp = (t0 > 0) ? hbase[(size_t)(t0-1)*Dc] : 0.f;
  float hv[TSF];
  #pragma unroll
  for (int t=0;t<TSF;++t) {
    hv[t] = hbase[(size_t)(t0+t)*Dc];
    acc += hv[t];
    float diff = acc - hp;
    hp = hv[t];
    float s = diff * diff;
    #pragma unroll
    for (int off=32; off; off>>=1) s += __shfl_down(s, off);
    if (!lane) redA[wv][t] = s;
  }
  float kk = kvec[l];
  float sp = kk > 0.f ? kk + log1pf(expf(-kk)) : log1pf(expf(kk));
  float w = expf(-sp);
  int ts = t0 - WARM; if (ts < 0) ts = 0;
  float s = 0.f;
  for (int t=ts; t<t0; ++t) s = hbase[(size_t)t*Dc] + w*s;
  __syncthreads();
  if (d < TSF) {
    float m = 0.f;
    #pragma unroll
    for (int w2=0;w2<8;++w2) m += redA[w2][d];
    mag[d] = sqrtf(m);
  }
  __syncthreads();
  #pragma unroll
  for (int t=0;t<TSF;++t) {
    s = hv[t] + w * s;
    float cv = mag[t] * fabsf(s);
    hv[t] = cv;
    float s1 = cv, s2 = cv * cv;
    #pragma unroll
    for (int off=32; off; off>>=1) {
      s1 += __shfl_down(s1, off);
      s2 += __shfl_down(s2, off);
    }
    if (!lane) { redA[wv][t] = s1; redB[wv][t] = s2; }
  }
  __syncthreads();
  if (d < TSF) {
    float m1 = 0.f, m2 = 0.f;
    #pragma unroll
    for (int w2=0;w2<8;++w2) { m1 += redA[w2][d]; m2 += redB[w2][d]; }
    float mu = m1 * (1.f/Dc);
    float var = fmaxf(m2 * (1.f/Dc) - mu*mu, 0.f);
    muS[d] = mu;
    rsS[d] = rsqrtf(var + 1e-3f);
  }
  __syncthreads();
  float gv = g[l*Dc + d], bv = bt[l*Dc + d];
  unsigned short* yp = yb + ((size_t)b*Tc + t0)*Dc + d;
  #pragma unroll
  for (int t=0;t<TSF;++t)
    yp[(size_t)t*Dc] = f2bf((hv[t] - muS[t]) * rsS[t] * gv + bv);
}

// ---------- W (L,R,C) fp32 -> Wt (L,C,R) bf16 ----------
__global__ __launch_bounds__(256) void transpose_to_bf16(
    const float* __restrict__ W, unsigned short* __restrict__ Wt, int R, int C)
{
  __shared__ float tile[32][33];
  int l = blockIdx.z;
  const float* Wl = W + (size_t)l * R * C;
  unsigned short* Wtl = Wt + (size_t)l * R * C;
  int c0 = blockIdx.x * 32, r0 = blockIdx.y * 32;
  int tx = threadIdx.x & 31, ty = threadIdx.x >> 5;
  for (int i = ty; i < 32; i += 8)
    tile[i][tx] = Wl[(size_t)(r0+i)*C + (c0+tx)];
  __syncthreads();
  for (int i = ty; i < 32; i += 8)
    Wtl[(size_t)(c0+i)*R + (r0+tx)] = f2bf(tile[tx][i]);
}

__global__ __launch_bounds__(256) void conv_bf16(
    const float* __restrict__ src, unsigned short* __restrict__ dst, int n)
{
  int i = blockIdx.x * 256 + threadIdx.x;
  if (i < n) dst[i] = f2bf(src[i]);
}

// ---------- bf16 MFMA GEMM, dbuf LDS, 1 barrier/K-step, XCD-aware grid ----
// A: MxK bf16 row-major. Bt: NxK bf16 row-major. C = A @ Bt^T.
// 1D grid: row = bid % nrow -> A-sharing blocks pinned to one XCD.
// EPI 0: Cb=bf16(gelu(z+bias)); 1: C+=z+bias (+ chunk partials via butterfly,
// + optional Cb=bf16); 2: C=z.
template<int CH> __device__ inline int swz(int row) {
  if constexpr (CH == 8) return row & 7;
  else return (row & 3) ^ ((row >> 3) & 1);
}

template<int EPI, int TM, int TN, int BK>
__global__ __launch_bounds__(256) void mgemm(
    const unsigned short* __restrict__ A,
    const unsigned short* __restrict__ Bt,
    const float* __restrict__ bias,
    float* __restrict__ C, unsigned short* __restrict__ Cb,
    float* __restrict__ part,
    int N, int K, int nrow)
{
  constexpr int CH = BK / 8;                   // 16B chunks per tile row
  constexpr int PA = TM*CH/256, PB = TN*CH/256;
  constexpr int WM = TM/2, WN = TN/2;
  constexpr int AM = WM/16, AN = WN/16;
  constexpr int NKH = BK/32;
  constexpr int ASTG = TM*BK, BSTG = TN*BK;    // shorts per LDS stage
  __shared__ unsigned short As[2*ASTG];
  __shared__ unsigned short Bs[2*BSTG];
  int tid = threadIdx.x;
  int lane = tid & 63, w = tid >> 6;
  int wr = w >> 1, wc = w & 1;
  int bid = blockIdx.x;
  int m0 = (bid % nrow) * TM, n0 = (bid / nrow) * TN;

  const unsigned short* ag[PA];
  const unsigned short* bg[PB];
  int aldst[PA], bldst[PB];
  #pragma unroll
  for (int p=0;p<PA;++p) {
    int ci = p*256 + tid;
    int row = ci / CH, cp = ci % CH;
    int cg = cp ^ swz<CH>(row);
    ag[p] = A + (size_t)(m0+row)*K + cg*8;
    aldst[p] = (p*256 + w*64)*8;               // wave-uniform LDS base
  }
  #pragma unroll
  for (int p=0;p<PB;++p) {
    int ci = p*256 + tid;
    int row = ci / CH, cp = ci % CH;
    int cg = cp ^ swz<CH>(row);
    bg[p] = Bt + (size_t)(n0+row)*K + cg*8;
    bldst[p] = (p*256 + w*64)*8;
  }

  int r = lane & 15, quad = lane >> 4;
  int aoff[NKH][AM], boff[NKH][AN];
  #pragma unroll
  for (int kh=0;kh<NKH;++kh) {
    int cb = kh*4 + quad;
    #pragma unroll
    for (int i=0;i<AM;++i)
      aoff[kh][i] = (wr*WM + i*16 + r)*BK + ((cb ^ swz<CH>(r)) & (CH-1))*8;
    #pragma unroll
    for (int j=0;j<AN;++j)
      boff[kh][j] = (wc*WN + j*16 + r)*BK + ((cb ^ swz<CH>(r)) & (CH-1))*8;
  }

  f32x4 acc[AM][AN];
  #pragma unroll
  for (int i=0;i<AM;++i)
    #pragma unroll
    for (int j=0;j<AN;++j)
      acc[i][j] = (f32x4){0.f,0.f,0.f,0.f};

  // prologue: stage 0
  #pragma unroll
  for (int p=0;p<PA;++p) gload_lds16(ag[p], &As[aldst[p]]);
  #pragma unroll
  for (int p=0;p<PB;++p) gload_lds16(bg[p], &Bs[bldst[p]]);

  int nk = K / BK;
  for (int ki = 0; ki < nk; ++ki) {
    __syncthreads();                           // stage cur complete
    int cur = ki & 1, nxt = cur ^ 1;
    if (ki + 1 < nk) {                         // prefetch overlaps compute
      int kk = (ki + 1) * BK;
      #pragma unroll
      for (int p=0;p<PA;++p) gload_lds16(ag[p] + kk, &As[nxt*ASTG + aldst[p]]);
      #pragma unroll
      for (int p=0;p<PB;++p) gload_lds16(bg[p] + kk, &Bs[nxt*BSTG + bldst[p]]);
    }
    #pragma unroll
    for (int kh=0;kh<NKH;++kh) {
      short8 af[AM], bfr[AN];
      #pragma unroll
      for (int i=0;i<AM;++i) af[i]  = *(const short8*)&As[cur*ASTG + aoff[kh][i]];
      #pragma unroll
      for (int j=0;j<AN;++j) bfr[j] = *(const short8*)&Bs[cur*BSTG + boff[kh][j]];
      #pragma unroll
      for (int i=0;i<AM;++i)
        #pragma unroll
        for (int j=0;j<AN;++j)
          acc[i][j] = __builtin_amdgcn_mfma_f32_16x16x32_bf16(af[i], bfr[j], acc[i][j], 0, 0, 0);
    }
  }

  #pragma unroll
  for (int i=0;i<AM;++i) {
    int rowb = m0 + wr*WM + i*16 + quad*4;
    #pragma unroll
    for (int j=0;j<AN;++j) {
      int col = n0 + wc*WN + j*16 + r;
      float bv = 0.f;
      if (EPI != 2) bv = bias[col];
      float ps = 0.f;
      #pragma unroll
      for (int reg=0;reg<4;++reg) {
        size_t idx = (size_t)(rowb + reg) * N + col;
        float z = acc[i][j][reg] + bv;
        if (EPI == 0) {
          z = 0.5f * z * (1.0f + erff(z * 0.707106781186547524f));
          Cb[idx] = f2bf(z);
        } else if (EPI == 1) {
          float hv = C[idx] + z;
          C[idx] = hv;
          ps += hv;
          if (Cb) Cb[idx] = f2bf(hv);
        } else {
          C[idx] = z;
        }
      }
      if (EPI == 1 && part) {
        // chunk (16 rows) sum: butterfly over quad bits (lanes ^16, ^32)
        ps += __shfl_xor(ps, 16);
        ps += __shfl_xor(ps, 32);
        if (quad == 0) {
          int chunk = (m0 + wr*WM + i*16) >> 4;   // TSF=16
          part[(size_t)chunk * N + col] = ps;
        }
      }
    }
  }
}

extern "C" void kernel_launch(void* const* d_in, const int* in_sizes, int n_in,
                              void* d_out, int out_size, void* d_ws, size_t ws_size,
                              hipStream_t stream) {
  const int*   x     = (const int*)  d_in[0];
  const float* embed = (const float*)d_in[1];
  const float* kvec  = (const float*)d_in[2];
  const float* g     = (const float*)d_in[3];
  const float* bt    = (const float*)d_in[4];
  const float* W1    = (const float*)d_in[5];
  const float* b1    = (const float*)d_in[6];
  const float* W2    = (const float*)d_in[7];
  const float* b2    = (const float*)d_in[8];
  float* out = (float*)d_out;

  const size_t NTD = (size_t)Bc * Tc * Dc;   // 4,194,304
  const size_t NTH = (size_t)Bc * Tc * Hc;   // 16,777,216
  char* wsb = (char*)d_ws;
  float* h      = (float*)wsb;                wsb += NTD*4;               // 16MB
  float* tmpA   = (float*)wsb;                wsb += NTD*4;               // 16MB
  float* partA  = (float*)wsb;                wsb += (size_t)Bc*NCF*Dc*4; // 1MB
  float* partB  = (float*)wsb;                wsb += (size_t)Bc*NCF*Dc*4; // 1MB
  unsigned short* yb   = (unsigned short*)wsb; wsb += NTD*2;              // 8MB
  unsigned short* a1b  = (unsigned short*)wsb; wsb += NTH*2;              // 32MB
  unsigned short* hb   = (unsigned short*)wsb; wsb += NTD*2;              // 8MB
  unsigned short* W1t  = (unsigned short*)wsb; wsb += (size_t)3*Dc*Hc*2;  // 6MB
  unsigned short* W2t  = (unsigned short*)wsb; wsb += (size_t)3*Dc*Hc*2;  // 6MB
  unsigned short* emb  = (unsigned short*)wsb; wsb += (size_t)Vc*Dc*2;

  // weight prep (per call)
  transpose_to_bf16<<<dim3(Hc/32, Dc/32, 3), 256, 0, stream>>>(W1, W1t, Dc, Hc);
  transpose_to_bf16<<<dim3(Dc/32, Hc/32, 3), 256, 0, stream>>>(W2, W2t, Hc, Dc);
  conv_bf16<<<dim3(Vc*Dc/256), 256, 0, stream>>>(embed, emb, Vc*Dc);

  // prologue
  embed_boundary<<<dim3(Bc*Tc/4), 256, 0, stream>>>(x, embed, tmpA);
  part_sums<<<dim3(NCF, Bc), 512, 0, stream>>>(tmpA, partA);
  part_prefix<<<dim3(256), 512, 0, stream>>>(partA);
  bd_apply<<<dim3(NCF, Bc), 512, 0, stream>>>(tmpA, partA, x, embed, h, partB);
  part_prefix<<<dim3(256), 512, 0, stream>>>(partB);

  for (int l = 0; l < 3; ++l) {
    mag_scan_ln<<<dim3(NCF, Bc), 512, 0, stream>>>(h, partB, kvec, l, g, bt, yb);
    // z = gelu(y @ W1 + b1): M=8192 N=2048 K=512; 64x128 tile -> 2048 blocks
    mgemm<0,64,128,32><<<dim3(128*(Hc/128)), 256, 0, stream>>>(
        yb, W1t + (size_t)l*Hc*Dc, b1 + (size_t)l*Hc, nullptr, a1b, nullptr,
        Hc, Dc, 128);
    // h += z @ W2 + b2 (+ h chunk partials): 64x64 tile, BK=64 -> 1024 blocks
    mgemm<1,64,64,64><<<dim3(128*(Dc/64)), 256, 0, stream>>>(
        a1b, W2t + (size_t)l*Dc*Hc, b2 + (size_t)l*Dc, h,
        (l == 2) ? hb : nullptr, (l < 2) ? partB : nullptr, Dc, Hc, 128);
    if (l < 2) part_prefix<<<dim3(256), 512, 0, stream>>>(partB);
  }
  // out = h @ embed^T: M=8192 N=256 K=512; 64x64 tiles, nrow=128
  mgemm<2,64,64,32><<<dim3(128*(Vc/64)), 256, 0, stream>>>(
      hb, emb, nullptr, out, nullptr, nullptr, Vc, Dc, 128);
}